// Round 3
// baseline (373.493 us; speedup 1.0000x reference)
//
#include <hip/hip_runtime.h>
#include <hip/hip_cooperative_groups.h>
#include <hip/hip_fp16.h>
#include <math.h>

namespace cg = cooperative_groups;

#define NEG_SLOPE 0.2f

typedef _Float16 h8 __attribute__((ext_vector_type(8)));
typedef float f4 __attribute__((ext_vector_type(4)));

// ---------------- fp16 pack/unpack helpers ----------------

__device__ inline float2 up2(unsigned u) {
    __half2 h;
    __builtin_memcpy(&h, &u, 4);
    return __half22float2(h);
}
__device__ inline unsigned pk2(float a, float b) {
    __half2 h = __floats2half2_rn(a, b);
    unsigned u;
    __builtin_memcpy(&u, &h, 4);
    return u;
}
__device__ inline void fma8(float* acc, const uint4& v, float p) {
    float2 f;
    f = up2(v.x); acc[0] += f.x * p; acc[1] += f.y * p;
    f = up2(v.y); acc[2] += f.x * p; acc[3] += f.y * p;
    f = up2(v.z); acc[4] += f.x * p; acc[5] += f.y * p;
    f = up2(v.w); acc[6] += f.x * p; acc[7] += f.y * p;
}
__device__ inline float dot4(const float4& a, const float4& b) {
    return a.x * b.x + a.y * b.y + a.z * b.z + a.w * b.w;
}

// ---------------- device phase: MFMA GEMM + fused attn-score epilogue ----------
// 4 waves/block, 16 rows/wave, 64 rows/block tile; grid-stride over tiles.
// A frag: row=lane&15, k=(lane>>4)*8+j.  D frag: col=lane&15, row=(lane>>4)*4+r.

template <int K, int M, int H, bool A16>
__device__ void dev_gemm(float* tl_base, const void* __restrict__ xin,
                         const __half* __restrict__ Wp,
                         const float* __restrict__ al,
                         const float* __restrict__ ar,
                         __half* __restrict__ outh,
                         float* __restrict__ el,
                         float* __restrict__ er, int N) {
    constexpr int KS = K / 32;   // k-steps
    constexpr int CF = M / 16;   // column fragments
    constexpr int LDT = 133;     // padded fp32 LDS row stride
    constexpr int CH8 = M / 8;   // 8-col chunks per row
    constexpr int NC8 = CH8 / 4; // chunks per lane in read-back (4 lanes/row)
    const int tid = threadIdx.x;
    const int wid = tid >> 6, lane = tid & 63;
    const int lhi = lane >> 4, llo = lane & 15;
    float* wt = tl_base + wid * 16 * LDT;
    const float4* al4 = (const float4*)al;
    const float4* ar4 = (const float4*)ar;
    const int ntiles = (N + 63) >> 6;

    for (int tile = blockIdx.x; tile < ntiles; tile += gridDim.x) {
        const int rowbase = tile * 64 + wid * 16;
        f4 acc[CF];
#pragma unroll
        for (int c = 0; c < CF; ++c) acc[c] = f4{0.f, 0.f, 0.f, 0.f};

        const int arow = rowbase + llo;
        const bool aval = arow < N;
#pragma unroll
        for (int s = 0; s < KS; ++s) {
            h8 a = {};
            if (aval) {
                if constexpr (A16) {
                    const __half* xp = (const __half*)xin + (size_t)arow * K + s * 32 + lhi * 8;
                    a = *(const h8*)xp;
                } else {
                    const float4* xp = (const float4*)((const float*)xin + (size_t)arow * K +
                                                       s * 32 + lhi * 8);
                    float4 x0 = xp[0];
                    float4 x1 = xp[1];
                    a[0] = (_Float16)x0.x; a[1] = (_Float16)x0.y;
                    a[2] = (_Float16)x0.z; a[3] = (_Float16)x0.w;
                    a[4] = (_Float16)x1.x; a[5] = (_Float16)x1.y;
                    a[6] = (_Float16)x1.z; a[7] = (_Float16)x1.w;
                }
            }
#pragma unroll
            for (int c = 0; c < CF; ++c) {
                h8 b = *(const h8*)(Wp + (size_t)((c * KS + s) * 64 + lane) * 8);
                acc[c] = __builtin_amdgcn_mfma_f32_16x16x32_f16(a, b, acc[c], 0, 0, 0);
            }
        }

        // scatter D frags into the per-wave LDS tile (row = lhi*4+r, col = c*16+llo)
#pragma unroll
        for (int c = 0; c < CF; ++c) {
#pragma unroll
            for (int r = 0; r < 4; ++r)
                wt[(lhi * 4 + r) * LDT + c * 16 + llo] = acc[c][r];
        }
        // same-wave LDS RAW: compiler inserts lgkmcnt; no barrier needed

        // read back row-major: 4 lanes per row, interleaved 8-col chunks j8 = q + 4*i
        const int rrow = lane >> 2;
        const int q = lane & 3;
        const int grow = rowbase + rrow;
        float elp[H], erp[H];
#pragma unroll
        for (int h = 0; h < H; ++h) { elp[h] = 0.f; erp[h] = 0.f; }
#pragma unroll
        for (int i = 0; i < NC8; ++i) {
            int j8 = q + 4 * i;
            float4 v0 = *(float4*)&wt[rrow * LDT + 8 * j8];
            float4 v1 = *(float4*)&wt[rrow * LDT + 8 * j8 + 4];
            int h = (H == 2 && i >= NC8 / 2) ? 1 : 0;
            float4 a0 = al4[2 * j8], a1 = al4[2 * j8 + 1];
            float4 r0 = ar4[2 * j8], r1 = ar4[2 * j8 + 1];
            elp[h] += dot4(v0, a0) + dot4(v1, a1);
            erp[h] += dot4(v0, r0) + dot4(v1, r1);
            if (grow < N) {
                uint4 pkv;
                pkv.x = pk2(v0.x, v0.y);
                pkv.y = pk2(v0.z, v0.w);
                pkv.z = pk2(v1.x, v1.y);
                pkv.w = pk2(v1.z, v1.w);
                *(uint4*)(outh + (size_t)grow * M + 8 * j8) = pkv;
            }
        }
#pragma unroll
        for (int h = 0; h < H; ++h) {
#pragma unroll
            for (int off = 1; off < 4; off <<= 1) {
                elp[h] += __shfl_xor(elp[h], off);
                erp[h] += __shfl_xor(erp[h], off);
            }
        }
        if (q == 0 && grow < N) {
            if constexpr (H == 2) {
                *(float2*)&el[(size_t)grow * 2] = float2{elp[0], elp[1]};
                *(float2*)&er[(size_t)grow * 2] = float2{erp[0], erp[1]};
            } else {
                el[grow] = elp[0];
                er[grow] = erp[0];
            }
        }
    }
}

// ---------------- device phase: softmax + aggregation (half-wave per dst) -------

template <int H, int D, int FSTRIDE, int T, bool OUT16>
__device__ void dev_agg(const __half* __restrict__ feat,
                        const float* __restrict__ el,
                        const float* __restrict__ er,
                        const int* __restrict__ row_start,
                        const int* __restrict__ csr_src,
                        const float* __restrict__ bias,
                        void* __restrict__ out, int N) {
    constexpr int NLp = FSTRIDE / 8;   // lanes per padded row (uint4 each)
    constexpr int GnH = 32 / NLp;      // edge groups per half-wave
    constexpr int BATCH = GnH * T;     // edges per gather round per half
    constexpr int WL = (H * D) / 8;    // writer lanes per dst
    static_assert(32 % NLp == 0 && BATCH <= 32, "layout");
    const int lane = threadIdx.x & 63;
    const int wid = threadIdx.x >> 6;
    const int l32 = lane & 31;
    const int hb = lane & 32;
    const int g = l32 / NLp;
    const int ln = l32 % NLp;
    const int npairs = (N + 1) >> 1;

    for (int pair = blockIdx.x * 4 + wid; pair < npairs; pair += gridDim.x * 4) {
        const int dstn = pair * 2 + (lane >> 5);
        const bool dval = dstn < N;
        int beg = dval ? row_start[dstn] : 0;
        int end = dval ? row_start[dstn + 1] : 0;
        int cnt = end - beg;

        float er_d[H];
#pragma unroll
        for (int h = 0; h < H; ++h) er_d[h] = dval ? er[(size_t)dstn * H + h] : 0.f;

        float ssum[H];
        float acc8[8];
#pragma unroll
        for (int h = 0; h < H; ++h) ssum[h] = 0.f;
#pragma unroll
        for (int i = 0; i < 8; ++i) acc8[i] = 0.f;

        int trips = (cnt + 31) >> 5;
        {
            int to = __shfl_xor(trips, 32);
            trips = (to > trips) ? to : trips;
        }

        for (int it = 0; it < trips; ++it) {
            int base = beg + it * 32;
            int idx = base + l32;
            bool valid = idx < end;
            int s = csr_src[valid ? idx : beg];
            float p[H];
            if constexpr (H == 2) {
                float2 e2 = ((const float2*)el)[s];
                float e0 = e2.x + er_d[0];
                float e1 = e2.y + er_d[1];
                e0 = (e0 > 0.f) ? e0 : NEG_SLOPE * e0;
                e1 = (e1 > 0.f) ? e1 : NEG_SLOPE * e1;
                p[0] = valid ? __expf(e0) : 0.f;
                p[1] = valid ? __expf(e1) : 0.f;
                ssum[0] += p[0];
                ssum[1] += p[1];
            } else {
                float e = el[s] + er_d[0];
                e = (e > 0.f) ? e : NEG_SLOPE * e;
                p[0] = valid ? __expf(e) : 0.f;
                ssum[0] += p[0];
            }
            int cc = end - base;
            cc = (cc < 0) ? 0 : ((cc > 32) ? 32 : cc);
            int ccm = cc;
            {
                int o = __shfl_xor(ccm, 32);
                ccm = (o > ccm) ? o : ccm;
            }
            for (int j = 0; j < ccm; j += BATCH) {
                uint4 v[T];
#pragma unroll
                for (int t = 0; t < T; ++t) {
                    if (j + GnH * t < cc) {
                        int sj = __shfl(s, hb + j + GnH * t + g);
                        v[t] = ((const uint4*)(feat + (size_t)sj * FSTRIDE))[ln];
                    }
                }
#pragma unroll
                for (int t = 0; t < T; ++t) {
                    if (j + GnH * t < cc) {
                        int slot = hb + j + GnH * t + g;
                        float pj = __shfl(p[0], slot);
                        if constexpr (H == 2) {
                            float pj1 = __shfl(p[1], slot);
                            pj = (ln >= 8) ? pj1 : pj;
                        }
                        fma8(acc8, v[t], pj);
                    }
                }
            }
        }

#pragma unroll
        for (int h = 0; h < H; ++h)
#pragma unroll
            for (int off = 16; off; off >>= 1) ssum[h] += __shfl_xor(ssum[h], off);
#pragma unroll
        for (int i = 0; i < 8; ++i) {
#pragma unroll
            for (int off = NLp; off < 32; off <<= 1) acc8[i] += __shfl_xor(acc8[i], off);
        }
        if (l32 < WL && dval) {
            float inv;
            if constexpr (H == 2) inv = 1.f / ((l32 >= 8) ? ssum[1] : ssum[0]);
            else inv = 1.f / ssum[0];
            const float4* bp = (const float4*)bias;
            float4 bv0 = bp[2 * l32], bv1 = bp[2 * l32 + 1];
            float4 o0, o1;
            o0.x = acc8[0] * inv + bv0.x; o0.y = acc8[1] * inv + bv0.y;
            o0.z = acc8[2] * inv + bv0.z; o0.w = acc8[3] * inv + bv0.w;
            o1.x = acc8[4] * inv + bv1.x; o1.y = acc8[5] * inv + bv1.y;
            o1.z = acc8[6] * inv + bv1.z; o1.w = acc8[7] * inv + bv1.w;
            if constexpr (OUT16) {
                __half* op = (__half*)out + (size_t)dstn * (H * D);
                uint4 pkv;
                pkv.x = pk2(o0.x, o0.y);
                pkv.y = pk2(o0.z, o0.w);
                pkv.z = pk2(o1.x, o1.y);
                pkv.w = pk2(o1.z, o1.w);
                ((uint4*)op)[l32] = pkv;
            } else {
                float4* op = (float4*)((float*)out + (size_t)dstn * (H * D));
                op[2 * l32] = o0;
                op[2 * l32 + 1] = o1;
            }
        }
    }
}

// ---------------- the cooperative mega-kernel ----------------

__global__ __launch_bounds__(256) void mega(
    const float* __restrict__ in_feat, const int* __restrict__ src,
    const int* __restrict__ dst,
    const float* __restrict__ W0, const float* __restrict__ al0,
    const float* __restrict__ ar0, const float* __restrict__ b0,
    const float* __restrict__ W1, const float* __restrict__ al1,
    const float* __restrict__ ar1, const float* __restrict__ b1,
    const float* __restrict__ W2, const float* __restrict__ al2,
    const float* __restrict__ ar2, const float* __restrict__ b2,
    float* __restrict__ out,
    int* __restrict__ deg, int* __restrict__ row_start,
    int* __restrict__ csr_src, int* __restrict__ rank, int* __restrict__ partial,
    __half* __restrict__ feat, float* __restrict__ el, float* __restrict__ er,
    __half* __restrict__ h0h, __half* __restrict__ h1h,
    __half* __restrict__ Wp0, __half* __restrict__ Wp1, __half* __restrict__ Wp2,
    float* __restrict__ al2p, float* __restrict__ ar2p, int N, int E) {
    cg::grid_group grid = cg::this_grid();
    __shared__ float sm_f[4 * 16 * 133];  // 34048 B: gemm tiles / scan scratch
    int* sm_i = (int*)sm_f;               // [0..255]=scan buf, [256..259]=wsum
    const int t = threadIdx.x;
    const int gt = blockIdx.x * 256 + t;
    const int gsz = gridDim.x * 256;

    // --- Phase A: zero deg + pack W (fp16 fragment-major) + pad al2/ar2 ---
    for (int i = gt; i < N; i += gsz) deg[i] = 0;
    if (blockIdx.x < 14) {
        const float* W;
        __half* P;
        int K, M, Msrc, lb = blockIdx.x;
        if (lb < 8) {
            W = W0; P = Wp0; K = 128; M = 128; Msrc = 128;
        } else if (lb < 12) {
            W = W1; P = Wp1; K = 128; M = 64; Msrc = 64; lb -= 8;
        } else {
            W = W2; P = Wp2; K = 64; M = 64; Msrc = 40; lb -= 12;
        }
        int tt = lb * 256 + t;  // indexes (m, k8)
        int nk8 = K >> 3;
        if (tt < M * nk8) {
            int m = tt % M, k8 = tt / M;
            int k = k8 * 8;
            int c = m >> 4, s = k >> 5, hi = (k >> 3) & 3, lane = hi * 16 + (m & 15);
            float v[8];
#pragma unroll
            for (int i = 0; i < 8; ++i)
                v[i] = (m < Msrc) ? W[(size_t)(k + i) * Msrc + m] : 0.f;
            uint4 o;
            o.x = pk2(v[0], v[1]);
            o.y = pk2(v[2], v[3]);
            o.z = pk2(v[4], v[5]);
            o.w = pk2(v[6], v[7]);
            *(uint4*)(P + (size_t)((c * (K >> 5) + s) * 64 + lane) * 8) = o;
        }
    } else if (blockIdx.x == 14 && t < 64) {
        al2p[t] = (t < 40) ? al2[t] : 0.f;
        ar2p[t] = (t < 40) ? ar2[t] : 0.f;
    }
    grid.sync();

    // --- Phase B: gemm L0 (needs Wp0) + degree histogram (independent) ---
    dev_gemm<128, 128, 2, false>(sm_f, in_feat, Wp0, al0, ar0, feat, el, er, N);
    for (int e = gt; e < E; e += gsz) {
        int d = dst[e];
        rank[e] = atomicAdd(&deg[d], 1);
    }
    grid.sync();

    // --- Phase C: per-chunk degree sums ---
    for (int b = blockIdx.x; b * 256 < N; b += gridDim.x) {
        int i = b * 256 + t;
        int v = (i < N) ? deg[i] : 0;
#pragma unroll
        for (int off = 32; off; off >>= 1) v += __shfl_xor(v, off);
        if ((t & 63) == 0) sm_i[256 + (t >> 6)] = v;
        __syncthreads();
        if (t == 0) partial[b] = sm_i[256] + sm_i[257] + sm_i[258] + sm_i[259];
        __syncthreads();
    }
    grid.sync();

    // --- Phase D: chunk-local scan + global prefix -> row_start ---
    for (int b = blockIdx.x; b * 256 < N; b += gridDim.x) {
        int i = b * 256 + t;
        int v = (i < N) ? deg[i] : 0;
        sm_i[t] = v;
        __syncthreads();
        for (int off = 1; off < 256; off <<= 1) {
            int x = (t >= off) ? sm_i[t - off] : 0;
            __syncthreads();
            sm_i[t] += x;
            __syncthreads();
        }
        int incl = sm_i[t];
        int pv = (t < b) ? partial[t] : 0;
#pragma unroll
        for (int off = 32; off; off >>= 1) pv += __shfl_xor(pv, off);
        if ((t & 63) == 0) sm_i[256 + (t >> 6)] = pv;
        __syncthreads();
        int pre = sm_i[256] + sm_i[257] + sm_i[258] + sm_i[259];
        if (i < N) row_start[i] = pre + incl - v;
        if (i == N - 1) row_start[N] = pre + incl;
        __syncthreads();
    }
    grid.sync();

    // --- Phase E: scatter edges into CSR ---
    for (int e = gt; e < E; e += gsz) {
        csr_src[row_start[dst[e]] + rank[e]] = src[e];
    }
    grid.sync();

    // --- Phase F: aggregate layer 0 ---
    dev_agg<2, 64, 128, 8, true>(feat, el, er, row_start, csr_src, b0, h0h, N);
    grid.sync();

    // --- Phase G: gemm L1 ---
    dev_gemm<128, 64, 1, true>(sm_f, h0h, Wp1, al1, ar1, feat, el, er, N);
    grid.sync();

    // --- Phase H: aggregate layer 1 ---
    dev_agg<1, 64, 64, 8, true>(feat, el, er, row_start, csr_src, b1, h1h, N);
    grid.sync();

    // --- Phase I: gemm L2 (M=64 padded; cols 40-63 exact zeros) ---
    dev_gemm<64, 64, 1, true>(sm_f, h1h, Wp2, al2p, ar2p, feat, el, er, N);
    grid.sync();

    // --- Phase J: aggregate layer 2 -> out ---
    dev_agg<1, 40, 64, 8, false>(feat, el, er, row_start, csr_src, b2, out, N);
}

// ================= legacy multi-kernel fallback (R2 path) =================

__global__ __launch_bounds__(256) void prep(const float* __restrict__ W0,
                                            const float* __restrict__ W1,
                                            const float* __restrict__ W2,
                                            const float* __restrict__ al2,
                                            const float* __restrict__ ar2,
                                            __half* __restrict__ P0,
                                            __half* __restrict__ P1,
                                            __half* __restrict__ P2,
                                            float* __restrict__ al2p,
                                            float* __restrict__ ar2p,
                                            int* __restrict__ deg, int N) {
    int b = blockIdx.x;
    int gtid = b * 256 + threadIdx.x;
    for (int i = gtid; i < N; i += gridDim.x * 256) deg[i] = 0;

    if (b < 14) {
        const float* W;
        __half* P;
        int K, M, Msrc, lb = b;
        if (lb < 8) {
            W = W0; P = P0; K = 128; M = 128; Msrc = 128;
        } else if (lb < 12) {
            W = W1; P = P1; K = 128; M = 64; Msrc = 64; lb -= 8;
        } else {
            W = W2; P = P2; K = 64; M = 64; Msrc = 40; lb -= 12;
        }
        int t = lb * 256 + threadIdx.x;
        int nk8 = K >> 3;
        if (t < M * nk8) {
            int m = t % M, k8 = t / M;
            int k = k8 * 8;
            int c = m >> 4, s = k >> 5, hi = (k >> 3) & 3, lane = hi * 16 + (m & 15);
            float v[8];
#pragma unroll
            for (int i = 0; i < 8; ++i)
                v[i] = (m < Msrc) ? W[(size_t)(k + i) * Msrc + m] : 0.f;
            uint4 o;
            o.x = pk2(v[0], v[1]);
            o.y = pk2(v[2], v[3]);
            o.z = pk2(v[4], v[5]);
            o.w = pk2(v[6], v[7]);
            *(uint4*)(P + (size_t)((c * (K >> 5) + s) * 64 + lane) * 8) = o;
        }
    } else if (b == 14) {
        int t = threadIdx.x;
        if (t < 64) {
            al2p[t] = (t < 40) ? al2[t] : 0.f;
            ar2p[t] = (t < 40) ? ar2[t] : 0.f;
        }
    }
}

__global__ __launch_bounds__(256) void degree_hist_rank(const int* __restrict__ dst,
                                                        int* __restrict__ deg,
                                                        int* __restrict__ rank, int E) {
    int e = blockIdx.x * blockDim.x + threadIdx.x;
    if (e >= E) return;
    int d = __builtin_nontemporal_load(&dst[e]);
    int r = atomicAdd(&deg[d], 1);
    __builtin_nontemporal_store(r, &rank[e]);
}

__global__ __launch_bounds__(256) void scan_block_sums(const int* __restrict__ in,
                                                       int* __restrict__ partial, int n) {
    int i = blockIdx.x * 256 + threadIdx.x;
    int v = (i < n) ? in[i] : 0;
#pragma unroll
    for (int off = 32; off; off >>= 1) v += __shfl_xor(v, off);
    __shared__ int wsum[4];
    if ((threadIdx.x & 63) == 0) wsum[threadIdx.x >> 6] = v;
    __syncthreads();
    if (threadIdx.x == 0) partial[blockIdx.x] = wsum[0] + wsum[1] + wsum[2] + wsum[3];
}

__global__ __launch_bounds__(256) void scan_final2(const int* __restrict__ in,
                                                   const int* __restrict__ partial,
                                                   int* __restrict__ out, int n) {
    __shared__ int buf[256];
    __shared__ int wsum[4];
    int t = threadIdx.x;
    int i = blockIdx.x * 256 + t;
    int v = (i < n) ? in[i] : 0;
    buf[t] = v;
    __syncthreads();
    for (int off = 1; off < 256; off <<= 1) {
        int x = (t >= off) ? buf[t - off] : 0;
        __syncthreads();
        buf[t] += x;
        __syncthreads();
    }
    int incl = buf[t];
    int pv = (t < blockIdx.x) ? partial[t] : 0;
#pragma unroll
    for (int off = 32; off; off >>= 1) pv += __shfl_xor(pv, off);
    if ((t & 63) == 0) wsum[t >> 6] = pv;
    __syncthreads();
    int pre = wsum[0] + wsum[1] + wsum[2] + wsum[3];
    if (i < n) out[i] = pre + incl - v;
    if (i == n - 1) out[n] = pre + incl;
}

__global__ __launch_bounds__(256) void scatter_rank(const int* __restrict__ src,
                                                    const int* __restrict__ dst,
                                                    const int* __restrict__ rank,
                                                    const int* __restrict__ row_start,
                                                    int* __restrict__ csr_src, int E) {
    int e = blockIdx.x * blockDim.x + threadIdx.x;
    if (e >= E) return;
    int d = __builtin_nontemporal_load(&dst[e]);
    int s = __builtin_nontemporal_load(&src[e]);
    int r = __builtin_nontemporal_load(&rank[e]);
    csr_src[row_start[d] + r] = s;
}

template <int K, int M, int H, bool A16>
__global__ __launch_bounds__(256) void gemm_mfma(const void* __restrict__ xin,
                                                 const __half* __restrict__ Wp,
                                                 const float* __restrict__ al,
                                                 const float* __restrict__ ar,
                                                 __half* __restrict__ outh,
                                                 float* __restrict__ el,
                                                 float* __restrict__ er, int N) {
    __shared__ float tl[4 * 16 * 133];
    dev_gemm<K, M, H, A16>(tl, xin, Wp, al, ar, outh, el, er, N);
}

template <int H, int D, int FSTRIDE, int T, bool OUT16>
__global__ __launch_bounds__(256) void gat_aggregate2(const __half* __restrict__ feat,
                                                      const float* __restrict__ el,
                                                      const float* __restrict__ er,
                                                      const int* __restrict__ row_start,
                                                      const int* __restrict__ csr_src,
                                                      const float* __restrict__ bias,
                                                      void* __restrict__ out, int N) {
    dev_agg<H, D, FSTRIDE, T, OUT16>(feat, el, er, row_start, csr_src, bias, out, N);
}

// ---------------- launch ----------------

extern "C" void kernel_launch(void* const* d_in, const int* in_sizes, int n_in,
                              void* d_out, int out_size, void* d_ws, size_t ws_size,
                              hipStream_t stream) {
    const float* in_feat = (const float*)d_in[0];
    const int*   src     = (const int*)d_in[1];
    const int*   dst     = (const int*)d_in[2];
    const float* W0 = (const float*)d_in[3];
    const float* al0 = (const float*)d_in[4];
    const float* ar0 = (const float*)d_in[5];
    const float* b0 = (const float*)d_in[6];
    const float* W1 = (const float*)d_in[7];
    const float* al1 = (const float*)d_in[8];
    const float* ar1 = (const float*)d_in[9];
    const float* b1 = (const float*)d_in[10];
    const float* W2 = (const float*)d_in[11];
    const float* al2 = (const float*)d_in[12];
    const float* ar2 = (const float*)d_in[13];
    const float* b2 = (const float*)d_in[14];
    float* out = (float*)d_out;

    const int N = in_sizes[0] / 128;  // 50000
    const int E = in_sizes[1];        // 850000

    char* ws = (char*)d_ws;
    auto alloc = [&](size_t bytes) -> void* {
        void* p = (void*)ws;
        ws += (bytes + 255) & ~(size_t)255;
        return p;
    };
    int* deg       = (int*)alloc((size_t)N * 4);
    int* row_start = (int*)alloc((size_t)(N + 1) * 4);
    int* csr_src   = (int*)alloc((size_t)E * 4);
    int* rank      = (int*)alloc((size_t)E * 4);
    int* partial   = (int*)alloc(256 * 4);
    __half* feat   = (__half*)alloc((size_t)N * 128 * 2);
    float* el      = (float*)alloc((size_t)N * 2 * 4);
    float* er      = (float*)alloc((size_t)N * 2 * 4);
    __half* h0h    = (__half*)alloc((size_t)N * 128 * 2);
    __half* h1h    = (__half*)alloc((size_t)N * 64 * 2);
    __half* Wp0    = (__half*)alloc((size_t)128 * 128 * 2);
    __half* Wp1    = (__half*)alloc((size_t)128 * 64 * 2);
    __half* Wp2    = (__half*)alloc((size_t)64 * 64 * 2);
    float* al2p    = (float*)alloc(64 * 4);
    float* ar2p    = (float*)alloc(64 * 4);

    // ---- cooperative mega-kernel path ----
    static int coop_grid = -2;
    if (coop_grid == -2) {
        int dev_sup = 0;
        if (hipDeviceGetAttribute(&dev_sup, hipDeviceAttributeCooperativeLaunch, 0) !=
                hipSuccess ||
            !dev_sup) {
            coop_grid = 0;
        } else {
            int per_cu = 0;
            hipError_t e =
                hipOccupancyMaxActiveBlocksPerMultiprocessor(&per_cu, mega, 256, 0);
            if (e != hipSuccess || per_cu <= 0) {
                coop_grid = 0;
            } else {
                coop_grid = per_cu * 256;  // 256 CUs on MI355X
                if (coop_grid > 1024) coop_grid = 1024;
            }
        }
    }
    if (coop_grid > 0) {
        void* args[] = {
            (void*)&in_feat, (void*)&src, (void*)&dst,
            (void*)&W0, (void*)&al0, (void*)&ar0, (void*)&b0,
            (void*)&W1, (void*)&al1, (void*)&ar1, (void*)&b1,
            (void*)&W2, (void*)&al2, (void*)&ar2, (void*)&b2,
            (void*)&out,
            (void*)&deg, (void*)&row_start, (void*)&csr_src, (void*)&rank,
            (void*)&partial,
            (void*)&feat, (void*)&el, (void*)&er, (void*)&h0h, (void*)&h1h,
            (void*)&Wp0, (void*)&Wp1, (void*)&Wp2, (void*)&al2p, (void*)&ar2p,
            (void*)&N, (void*)&E};
        hipError_t e = hipLaunchCooperativeKernel((const void*)mega, dim3(coop_grid),
                                                  dim3(256), args, 0, stream);
        if (e == hipSuccess) return;
        coop_grid = 0;  // fall back permanently
    }

    // ---- legacy multi-kernel path ----
    int egrid = (E + 255) / 256;
    int nb = (N + 255) / 256;

    prep<<<256, 256, 0, stream>>>(W0, W1, W2, al2, ar2, Wp0, Wp1, Wp2, al2p, ar2p, deg, N);
    degree_hist_rank<<<egrid, 256, 0, stream>>>(dst, deg, rank, E);
    scan_block_sums<<<nb, 256, 0, stream>>>(deg, partial, N);
    scan_final2<<<nb, 256, 0, stream>>>(deg, partial, row_start, N);
    scatter_rank<<<egrid, 256, 0, stream>>>(src, dst, rank, row_start, csr_src, E);

    int npairs = (N + 1) / 2;
    int pgrid = (npairs * 64 + 255) / 256;
    int mgrid = (N + 63) / 64;

    gemm_mfma<128, 128, 2, false><<<mgrid, 256, 0, stream>>>(in_feat, Wp0, al0, ar0, feat, el, er, N);
    gat_aggregate2<2, 64, 128, 8, true><<<pgrid, 256, 0, stream>>>(feat, el, er, row_start, csr_src, b0, h0h, N);

    gemm_mfma<128, 64, 1, true><<<mgrid, 256, 0, stream>>>(h0h, Wp1, al1, ar1, feat, el, er, N);
    gat_aggregate2<1, 64, 64, 8, true><<<pgrid, 256, 0, stream>>>(feat, el, er, row_start, csr_src, b1, h1h, N);

    gemm_mfma<64, 64, 1, true><<<mgrid, 256, 0, stream>>>(h1h, Wp2, al2p, ar2p, feat, el, er, N);
    gat_aggregate2<1, 40, 64, 8, false><<<pgrid, 256, 0, stream>>>(feat, el, er, row_start, csr_src, b2, out, N);
}

// Round 4
// 332.137 us; speedup vs baseline: 1.1245x; 1.1245x over previous
//
#include <hip/hip_runtime.h>
#include <hip/hip_fp16.h>
#include <math.h>

#define NEG_SLOPE 0.2f

typedef _Float16 h8 __attribute__((ext_vector_type(8)));
typedef float f4 __attribute__((ext_vector_type(4)));

// ---------------- fp16 pack/unpack helpers ----------------

__device__ inline float2 up2(unsigned u) {
    __half2 h;
    __builtin_memcpy(&h, &u, 4);
    return __half22float2(h);
}
__device__ inline unsigned pk2(float a, float b) {
    __half2 h = __floats2half2_rn(a, b);
    unsigned u;
    __builtin_memcpy(&u, &h, 4);
    return u;
}
__device__ inline void fma8(float* acc, const uint4& v, float p) {
    float2 f;
    f = up2(v.x); acc[0] += f.x * p; acc[1] += f.y * p;
    f = up2(v.y); acc[2] += f.x * p; acc[3] += f.y * p;
    f = up2(v.z); acc[4] += f.x * p; acc[5] += f.y * p;
    f = up2(v.w); acc[6] += f.x * p; acc[7] += f.y * p;
}
__device__ inline float dot4(const float4& a, const float4& b) {
    return a.x * b.x + a.y * b.y + a.z * b.z + a.w * b.w;
}

// ---------------- prep: zero deg + pack W (fp16 fragment-major) + pad al2/ar2 ----
// W element (k,m): cfrag c=m>>4, kstep s=k>>5, lane=((k>>3)&3)*16 + (m&15), j=k&7

__global__ __launch_bounds__(256) void prep(const float* __restrict__ W0,
                                            const float* __restrict__ W1,
                                            const float* __restrict__ W2,
                                            const float* __restrict__ al2,
                                            const float* __restrict__ ar2,
                                            __half* __restrict__ P0,
                                            __half* __restrict__ P1,
                                            __half* __restrict__ P2,
                                            float* __restrict__ al2p,
                                            float* __restrict__ ar2p,
                                            int* __restrict__ deg, int N) {
    int b = blockIdx.x;
    int gtid = b * 256 + threadIdx.x;
    for (int i = gtid; i < N; i += gridDim.x * 256) deg[i] = 0;

    if (b < 14) {
        const float* W;
        __half* P;
        int K, M, Msrc, lb = b;
        if (lb < 8) {
            W = W0; P = P0; K = 128; M = 128; Msrc = 128;
        } else if (lb < 12) {
            W = W1; P = P1; K = 128; M = 64; Msrc = 64; lb -= 8;
        } else {
            W = W2; P = P2; K = 64; M = 64; Msrc = 40; lb -= 12;
        }
        int t = lb * 256 + threadIdx.x;  // indexes (m, k8)
        int nk8 = K >> 3;
        if (t < M * nk8) {
            int m = t % M, k8 = t / M;
            int k = k8 * 8;
            int c = m >> 4, s = k >> 5, hi = (k >> 3) & 3, lane = hi * 16 + (m & 15);
            float v[8];
#pragma unroll
            for (int i = 0; i < 8; ++i)
                v[i] = (m < Msrc) ? W[(size_t)(k + i) * Msrc + m] : 0.f;
            uint4 o;
            o.x = pk2(v[0], v[1]);
            o.y = pk2(v[2], v[3]);
            o.z = pk2(v[4], v[5]);
            o.w = pk2(v[6], v[7]);
            *(uint4*)(P + (size_t)((c * (K >> 5) + s) * 64 + lane) * 8) = o;
        }
    } else if (b == 14) {
        int t = threadIdx.x;
        if (t < 64) {
            al2p[t] = (t < 40) ? al2[t] : 0.f;
            ar2p[t] = (t < 40) ? ar2[t] : 0.f;
        }
    }
}

// ---------------- CSR build ----------------

__global__ __launch_bounds__(256) void hist(const int* __restrict__ dst,
                                            int* __restrict__ deg, int E) {
    int e = blockIdx.x * blockDim.x + threadIdx.x;
    if (e >= E) return;
    atomicAdd(&deg[__builtin_nontemporal_load(&dst[e])], 1);
}

__global__ __launch_bounds__(256) void scan_block_sums(const int* __restrict__ in,
                                                       int* __restrict__ partial, int n) {
    int i = blockIdx.x * 256 + threadIdx.x;
    int v = (i < n) ? in[i] : 0;
#pragma unroll
    for (int off = 32; off; off >>= 1) v += __shfl_xor(v, off);
    __shared__ int wsum[4];
    if ((threadIdx.x & 63) == 0) wsum[threadIdx.x >> 6] = v;
    __syncthreads();
    if (threadIdx.x == 0) partial[blockIdx.x] = wsum[0] + wsum[1] + wsum[2] + wsum[3];
}

// merged offsets+final scan; each block reduces partial[0..bid) itself (nb<=256).
// writes row_start AND a cursor copy for the atomic scatter.
__global__ __launch_bounds__(256) void scan_final3(const int* __restrict__ in,
                                                   const int* __restrict__ partial,
                                                   int* __restrict__ out,
                                                   int* __restrict__ cursor, int n) {
    __shared__ int buf[256];
    __shared__ int wsum[4];
    int t = threadIdx.x;
    int i = blockIdx.x * 256 + t;
    int v = (i < n) ? in[i] : 0;
    buf[t] = v;
    __syncthreads();
    for (int off = 1; off < 256; off <<= 1) {
        int x = (t >= off) ? buf[t - off] : 0;
        __syncthreads();
        buf[t] += x;
        __syncthreads();
    }
    int incl = buf[t];
    int pv = (t < blockIdx.x) ? partial[t] : 0;
#pragma unroll
    for (int off = 32; off; off >>= 1) pv += __shfl_xor(pv, off);
    if ((t & 63) == 0) wsum[t >> 6] = pv;
    __syncthreads();
    int pre = wsum[0] + wsum[1] + wsum[2] + wsum[3];
    if (i < n) {
        int rs = pre + incl - v;
        out[i] = rs;
        cursor[i] = rs;
    }
    if (i == n - 1) out[n] = pre + incl;
}

// ---------------- GEMM tile (device) ----------------
// One 64-row (or 128-col) tile: 4 waves x 16 rows. B frags from packed global W.
// A frag: row=lane&15, k=(lane>>4)*8+j.  D frag: col=lane&15, row=(lane>>4)*4+r.
// AMODE: 0 = global fp32, 1 = global fp16, 2 = per-wave LDS fp16 (XOR-chunk swizzled)

template <int K, int M, int H, int AMODE, int LSTR>
__device__ __forceinline__ void gemm_tile(float* wt, const void* __restrict__ xin,
                                          const __half* aw,
                                          const __half* __restrict__ Wp,
                                          const float* __restrict__ al,
                                          const float* __restrict__ ar,
                                          __half* __restrict__ outh,
                                          float* __restrict__ el,
                                          float* __restrict__ er, int rowbase, int N) {
    constexpr int KS = K / 32;
    constexpr int CF = M / 16;
    constexpr int LDT = (M == 128) ? 133 : 69;  // padded fp32 transpose stride
    constexpr int NC8 = (M / 8) / 4;
    const int lane = threadIdx.x & 63;
    const int lhi = lane >> 4, llo = lane & 15;

    f4 acc[CF];
#pragma unroll
    for (int c = 0; c < CF; ++c) acc[c] = f4{0.f, 0.f, 0.f, 0.f};

    const int arow = rowbase + llo;
    const bool aval = arow < N;
#pragma unroll
    for (int s = 0; s < KS; ++s) {
        h8 a = {};
        if constexpr (AMODE == 2) {
            int c8 = s * 4 + lhi;
            a = *(const h8*)(aw + llo * LSTR + ((c8 ^ (llo & 7)) << 3));
        } else if constexpr (AMODE == 1) {
            if (aval)
                a = *(const h8*)((const __half*)xin + (size_t)arow * K + s * 32 + lhi * 8);
        } else {
            if (aval) {
                const float4* xp = (const float4*)((const float*)xin + (size_t)arow * K +
                                                   s * 32 + lhi * 8);
                float4 x0 = xp[0];
                float4 x1 = xp[1];
                a[0] = (_Float16)x0.x; a[1] = (_Float16)x0.y;
                a[2] = (_Float16)x0.z; a[3] = (_Float16)x0.w;
                a[4] = (_Float16)x1.x; a[5] = (_Float16)x1.y;
                a[6] = (_Float16)x1.z; a[7] = (_Float16)x1.w;
            }
        }
#pragma unroll
        for (int c = 0; c < CF; ++c) {
            h8 b = *(const h8*)(Wp + (size_t)((c * KS + s) * 64 + lane) * 8);
            acc[c] = __builtin_amdgcn_mfma_f32_16x16x32_f16(a, b, acc[c], 0, 0, 0);
        }
    }
    asm volatile("" ::: "memory");  // keep LDS A-reads before wt writes (wt may alias)

    // scatter D frags into per-wave transpose tile (row = lhi*4+r, col = c*16+llo)
#pragma unroll
    for (int c = 0; c < CF; ++c) {
#pragma unroll
        for (int r = 0; r < 4; ++r)
            wt[(lhi * 4 + r) * LDT + c * 16 + llo] = acc[c][r];
    }
    asm volatile("" ::: "memory");
    // (same-wave LDS RAW: DS pipe is in-order per wave)

    // read back row-major: 4 lanes per row, interleaved 8-col chunks j8 = q + 4*i
    const int rrow = lane >> 2;
    const int q = lane & 3;
    const int grow = rowbase + rrow;
    float elp[H], erp[H];
#pragma unroll
    for (int h = 0; h < H; ++h) { elp[h] = 0.f; erp[h] = 0.f; }
    const float4* al4 = (const float4*)al;
    const float4* ar4 = (const float4*)ar;
#pragma unroll
    for (int i = 0; i < NC8; ++i) {
        int j8 = q + 4 * i;
        float4 v0 = *(float4*)&wt[rrow * LDT + 8 * j8];
        float4 v1 = *(float4*)&wt[rrow * LDT + 8 * j8 + 4];
        int h = (H == 2 && i >= NC8 / 2) ? 1 : 0;
        float4 a0 = al4[2 * j8], a1 = al4[2 * j8 + 1];
        float4 r0 = ar4[2 * j8], r1 = ar4[2 * j8 + 1];
        elp[h] += dot4(v0, a0) + dot4(v1, a1);
        erp[h] += dot4(v0, r0) + dot4(v1, r1);
        if (grow < N) {
            uint4 pkv;
            pkv.x = pk2(v0.x, v0.y);
            pkv.y = pk2(v0.z, v0.w);
            pkv.z = pk2(v1.x, v1.y);
            pkv.w = pk2(v1.z, v1.w);
            *(uint4*)(outh + (size_t)grow * M + 8 * j8) = pkv;
        }
    }
#pragma unroll
    for (int h = 0; h < H; ++h) {
#pragma unroll
        for (int off = 1; off < 4; off <<= 1) {
            elp[h] += __shfl_xor(elp[h], off);
            erp[h] += __shfl_xor(erp[h], off);
        }
    }
    if (q == 0 && grow < N) {
        if constexpr (H == 2) {
            *(float2*)&el[(size_t)grow * 2] = float2{elp[0], elp[1]};
            *(float2*)&er[(size_t)grow * 2] = float2{erp[0], erp[1]};
        } else {
            el[grow] = elp[0];
            er[grow] = erp[0];
        }
    }
}

// ---------------- aggregate core: one dst-pair per wave ----------------
// lanes [0,32) own dstn of the low half, [32,64) the high half (caller encodes in dstn).
// Returns writer-lane outputs o0,o1 (valid for l32 < (H*D)/8; zeros when !dval).

template <int H, int D, int FSTRIDE, int T>
__device__ __forceinline__ void agg_one(const __half* __restrict__ feat,
                                        const float* __restrict__ el,
                                        const float* __restrict__ er,
                                        const int* __restrict__ row_start,
                                        const int* __restrict__ csr_src,
                                        const float* __restrict__ bias,
                                        int dstn, bool dval, int lane,
                                        float4& o0, float4& o1) {
    constexpr int NLp = FSTRIDE / 8;   // lanes per padded row (uint4 each)
    constexpr int GnH = 32 / NLp;      // edge groups per half-wave
    constexpr int BATCH = GnH * T;     // edges per gather round per half
    constexpr int WL = (H * D) / 8;    // writer lanes per dst
    static_assert(32 % NLp == 0 && BATCH <= 32, "layout");
    const int l32 = lane & 31;
    const int hb = lane & 32;
    const int g = l32 / NLp;
    const int ln = l32 % NLp;

    int beg = dval ? row_start[dstn] : 0;
    int end = dval ? row_start[dstn + 1] : 0;
    int cnt = end - beg;

    float er_d[H];
#pragma unroll
    for (int h = 0; h < H; ++h) er_d[h] = dval ? er[(size_t)dstn * H + h] : 0.f;

    float ssum[H];
    float acc8[8];
#pragma unroll
    for (int h = 0; h < H; ++h) ssum[h] = 0.f;
#pragma unroll
    for (int i = 0; i < 8; ++i) acc8[i] = 0.f;

    int trips = (cnt + 31) >> 5;
    {
        int to = __shfl_xor(trips, 32);
        trips = (to > trips) ? to : trips;
    }

    for (int it = 0; it < trips; ++it) {
        int base = beg + it * 32;
        int idx = base + l32;
        bool valid = idx < end;
        int s = csr_src[valid ? idx : beg];
        float p[H];
        if constexpr (H == 2) {
            float2 e2 = ((const float2*)el)[s];
            float e0 = e2.x + er_d[0];
            float e1 = e2.y + er_d[1];
            e0 = (e0 > 0.f) ? e0 : NEG_SLOPE * e0;
            e1 = (e1 > 0.f) ? e1 : NEG_SLOPE * e1;
            p[0] = valid ? __expf(e0) : 0.f;
            p[1] = valid ? __expf(e1) : 0.f;
            ssum[0] += p[0];
            ssum[1] += p[1];
        } else {
            float e = el[s] + er_d[0];
            e = (e > 0.f) ? e : NEG_SLOPE * e;
            p[0] = valid ? __expf(e) : 0.f;
            ssum[0] += p[0];
        }
        int cc = end - base;
        cc = (cc < 0) ? 0 : ((cc > 32) ? 32 : cc);
        int ccm = cc;
        {
            int o = __shfl_xor(ccm, 32);
            ccm = (o > ccm) ? o : ccm;
        }
        for (int j = 0; j < ccm; j += BATCH) {
            uint4 v[T];
#pragma unroll
            for (int t = 0; t < T; ++t) {
                if (j + GnH * t < cc) {
                    int sj = __shfl(s, hb + j + GnH * t + g);
                    v[t] = ((const uint4*)(feat + (size_t)sj * FSTRIDE))[ln];
                }
            }
#pragma unroll
            for (int t = 0; t < T; ++t) {
                if (j + GnH * t < cc) {
                    int slot = hb + j + GnH * t + g;
                    float pj = __shfl(p[0], slot);
                    if constexpr (H == 2) {
                        float pj1 = __shfl(p[1], slot);
                        pj = (ln >= 8) ? pj1 : pj;
                    }
                    fma8(acc8, v[t], pj);
                }
            }
        }
    }

#pragma unroll
    for (int h = 0; h < H; ++h)
#pragma unroll
        for (int off = 16; off; off >>= 1) ssum[h] += __shfl_xor(ssum[h], off);
#pragma unroll
    for (int i = 0; i < 8; ++i) {
#pragma unroll
        for (int off = NLp; off < 32; off <<= 1) acc8[i] += __shfl_xor(acc8[i], off);
    }
    o0 = float4{0.f, 0.f, 0.f, 0.f};
    o1 = float4{0.f, 0.f, 0.f, 0.f};
    if (l32 < WL) {
        float sden;
        if constexpr (H == 2) sden = (l32 >= 8) ? ssum[1] : ssum[0];
        else sden = ssum[0];
        float inv = (dval && sden > 0.f) ? 1.f / sden : 0.f;
        float bsc = dval ? 1.f : 0.f;
        const float4* bp = (const float4*)bias;
        float4 bv0 = bp[2 * l32], bv1 = bp[2 * l32 + 1];
        o0.x = (acc8[0] * inv + bv0.x) * bsc; o0.y = (acc8[1] * inv + bv0.y) * bsc;
        o0.z = (acc8[2] * inv + bv0.z) * bsc; o0.w = (acc8[3] * inv + bv0.w) * bsc;
        o1.x = (acc8[4] * inv + bv1.x) * bsc; o1.y = (acc8[5] * inv + bv1.y) * bsc;
        o1.z = (acc8[6] * inv + bv1.z) * bsc; o1.w = (acc8[7] * inv + bv1.w) * bsc;
    }
}

// ---------------- fused: scatter edges + gemm layer 0 (independent work) -------

__global__ __launch_bounds__(256) void scatter_gemm0(
    const int* __restrict__ src, const int* __restrict__ dst,
    int* __restrict__ cursor, int* __restrict__ csr_src,
    const float* __restrict__ in_feat, const __half* __restrict__ Wp0,
    const float* __restrict__ al0, const float* __restrict__ ar0,
    __half* __restrict__ feat0, float* __restrict__ el0, float* __restrict__ er0,
    int N, int E) {
    constexpr int LDT = 133;
    __shared__ float tl[4 * 16 * LDT];
    const int wid = threadIdx.x >> 6;
    const int ntiles = (N + 63) >> 6;
    if (blockIdx.x < ntiles) {
        gemm_tile<128, 128, 2, 0, 0>(tl + wid * 16 * LDT, in_feat, nullptr, Wp0, al0,
                                     ar0, feat0, el0, er0, blockIdx.x * 64 + wid * 16,
                                     N);
    }
    int e = blockIdx.x * 256 + threadIdx.x;
    if (e < E) {
        int d = __builtin_nontemporal_load(&dst[e]);
        int s = __builtin_nontemporal_load(&src[e]);
        int pos = atomicAdd(&cursor[d], 1);
        csr_src[pos] = s;
    }
}

// ---------------- fused: aggregate layer l -> (LDS) -> gemm layer l+1 ----------
// Block owns 64 dsts; wave w owns dsts [w*16, w*16+16) AND gemm rows [w*16, w*16+16)
// -> zero cross-wave LDS sharing -> no __syncthreads. Per-wave LDS region is a
// union of the fp16 h-tile (agg output / gemm A) and the fp32 transpose scratch
// (disjoint lifetimes; per-wave DS pipe is in-order).

template <int HA, int DA, int FSA, int T, int KG, int LSTR>
__global__ __launch_bounds__(256, 4) void agg_gemm(
    const __half* __restrict__ featA, const float* __restrict__ elA,
    const float* __restrict__ erA, const int* __restrict__ row_start,
    const int* __restrict__ csr_src, const float* __restrict__ biasA,
    const __half* __restrict__ Wp, const float* __restrict__ alG,
    const float* __restrict__ arG, __half* __restrict__ featO,
    float* __restrict__ elO, float* __restrict__ erO, int N) {
    constexpr int LDT = 69;
    constexpr int REGB = 16 * LDT * 4;  // 4416 B per-wave region
    static_assert(16 * LSTR * 2 <= REGB, "h-tile must fit region");
    static_assert(HA * DA == KG, "agg out feeds gemm K");
    constexpr int WL = (HA * DA) / 8;
    __shared__ alignas(16) char smem[4][REGB];
    const int lane = threadIdx.x & 63;
    const int wid = threadIdx.x >> 6;
    const int l32 = lane & 31;
    __half* lds_h = (__half*)&smem[wid][0];
    float* wt = (float*)&smem[wid][0];
    const int dbase = blockIdx.x * 64 + wid * 16;

#pragma unroll 1
    for (int it = 0; it < 8; ++it) {
        int dl = it * 2 + (lane >> 5);   // local row 0..15 within the wave
        int dstn = dbase + dl;
        bool dval = dstn < N;
        float4 o0, o1;
        agg_one<HA, DA, FSA, T>(featA, elA, erA, row_start, csr_src, biasA, dstn,
                                dval, lane, o0, o1);
        if (l32 < WL) {
            uint4 pkv;
            pkv.x = pk2(o0.x, o0.y);
            pkv.y = pk2(o0.z, o0.w);
            pkv.z = pk2(o1.x, o1.y);
            pkv.w = pk2(o1.z, o1.w);
            // XOR-chunk swizzle (chunk = 8 halfs) to decorrelate gemm A-read banks
            ((uint4*)(lds_h + dl * LSTR))[l32 ^ (dl & 7)] = pkv;
        }
    }
    asm volatile("" ::: "memory");

    gemm_tile<KG, 64, 1, 2, LSTR>(wt, nullptr, lds_h, Wp, alG, arG, featO, elO, erO,
                                  dbase, N);
}

// ---------------- standalone aggregate -> fp32 out (layer 2) ----------------

template <int H, int D, int FSTRIDE, int T>
__global__ __launch_bounds__(256) void gat_agg_out(const __half* __restrict__ feat,
                                                   const float* __restrict__ el,
                                                   const float* __restrict__ er,
                                                   const int* __restrict__ row_start,
                                                   const int* __restrict__ csr_src,
                                                   const float* __restrict__ bias,
                                                   float* __restrict__ out, int N) {
    int pair = (blockIdx.x * blockDim.x + threadIdx.x) >> 6;
    int lane = threadIdx.x & 63;
    if (pair * 2 >= N) return;
    int dstn = pair * 2 + (lane >> 5);
    bool dval = dstn < N;
    float4 o0, o1;
    agg_one<H, D, FSTRIDE, T>(feat, el, er, row_start, csr_src, bias, dstn, dval,
                              lane, o0, o1);
    constexpr int WL = (H * D) / 8;
    int l32 = lane & 31;
    if (l32 < WL && dval) {
        float4* op = (float4*)(out + (size_t)dstn * (H * D));
        op[2 * l32] = o0;
        op[2 * l32 + 1] = o1;
    }
}

// ---------------- launch ----------------

extern "C" void kernel_launch(void* const* d_in, const int* in_sizes, int n_in,
                              void* d_out, int out_size, void* d_ws, size_t ws_size,
                              hipStream_t stream) {
    const float* in_feat = (const float*)d_in[0];
    const int*   src     = (const int*)d_in[1];
    const int*   dst     = (const int*)d_in[2];
    const float* W0 = (const float*)d_in[3];
    const float* al0 = (const float*)d_in[4];
    const float* ar0 = (const float*)d_in[5];
    const float* b0 = (const float*)d_in[6];
    const float* W1 = (const float*)d_in[7];
    const float* al1 = (const float*)d_in[8];
    const float* ar1 = (const float*)d_in[9];
    const float* b1 = (const float*)d_in[10];
    const float* W2 = (const float*)d_in[11];
    const float* al2 = (const float*)d_in[12];
    const float* ar2 = (const float*)d_in[13];
    const float* b2 = (const float*)d_in[14];
    float* out = (float*)d_out;

    const int N = in_sizes[0] / 128;  // 50000
    const int E = in_sizes[1];        // 850000

    char* ws = (char*)d_ws;
    auto alloc = [&](size_t bytes) -> void* {
        void* p = (void*)ws;
        ws += (bytes + 255) & ~(size_t)255;
        return p;
    };
    int* deg       = (int*)alloc((size_t)N * 4);
    int* row_start = (int*)alloc((size_t)(N + 1) * 4);
    int* cursor    = (int*)alloc((size_t)N * 4);
    int* csr_src   = (int*)alloc((size_t)E * 4);
    int* partial   = (int*)alloc(256 * 4);
    __half* feat0  = (__half*)alloc((size_t)N * 128 * 2);
    float* el0     = (float*)alloc((size_t)N * 2 * 4);
    float* er0     = (float*)alloc((size_t)N * 2 * 4);
    __half* feat1  = (__half*)alloc((size_t)N * 64 * 2);
    float* el1     = (float*)alloc((size_t)N * 4);
    float* er1     = (float*)alloc((size_t)N * 4);
    __half* feat2  = (__half*)alloc((size_t)N * 64 * 2);
    float* el2     = (float*)alloc((size_t)N * 4);
    float* er2     = (float*)alloc((size_t)N * 4);
    __half* Wp0    = (__half*)alloc((size_t)128 * 128 * 2);
    __half* Wp1    = (__half*)alloc((size_t)128 * 64 * 2);
    __half* Wp2    = (__half*)alloc((size_t)64 * 64 * 2);
    float* al2p    = (float*)alloc(64 * 4);
    float* ar2p    = (float*)alloc(64 * 4);

    int egrid = (E + 255) / 256;     // 3321
    int nb = (N + 255) / 256;        // 196
    int ntiles = (N + 63) / 64;      // 782
    int pgrid = (((N + 1) / 2) * 64 + 255) / 256;

    prep<<<256, 256, 0, stream>>>(W0, W1, W2, al2, ar2, Wp0, Wp1, Wp2, al2p, ar2p,
                                  deg, N);
    hist<<<egrid, 256, 0, stream>>>(dst, deg, E);
    scan_block_sums<<<nb, 256, 0, stream>>>(deg, partial, N);
    scan_final3<<<nb, 256, 0, stream>>>(deg, partial, row_start, cursor, N);
    // scatter (CSR fill) + gemm L0 are independent: one dispatch
    scatter_gemm0<<<egrid, 256, 0, stream>>>(src, dst, cursor, csr_src, in_feat, Wp0,
                                             al0, ar0, feat0, el0, er0, N, E);
    // agg L0 -> LDS -> gemm L1
    agg_gemm<2, 64, 128, 8, 128, 136><<<ntiles, 256, 0, stream>>>(
        feat0, el0, er0, row_start, csr_src, b0, Wp1, al1, ar1, feat1, el1, er1, N);
    // agg L1 -> LDS -> gemm L2 (M=64 padded; cols 40-63 exact zeros)
    agg_gemm<1, 64, 64, 8, 64, 72><<<ntiles, 256, 0, stream>>>(
        feat1, el1, er1, row_start, csr_src, b1, Wp2, al2p, ar2p, feat2, el2, er2, N);
    // agg L2 -> out
    gat_agg_out<1, 40, 64, 8><<<pgrid, 256, 0, stream>>>(feat2, el2, er2, row_start,
                                                         csr_src, b2, out, N);
}

// Round 5
// 287.653 us; speedup vs baseline: 1.2984x; 1.1546x over previous
//
#include <hip/hip_runtime.h>
#include <hip/hip_fp16.h>
#include <math.h>

#define NEG_SLOPE 0.2f

typedef _Float16 h8 __attribute__((ext_vector_type(8)));
typedef float f4 __attribute__((ext_vector_type(4)));

// ---------------- fp16 pack/unpack helpers ----------------

__device__ inline float2 up2(unsigned u) {
    __half2 h;
    __builtin_memcpy(&h, &u, 4);
    return __half22float2(h);
}
__device__ inline unsigned pk2(float a, float b) {
    __half2 h = __floats2half2_rn(a, b);
    unsigned u;
    __builtin_memcpy(&u, &h, 4);
    return u;
}
__device__ inline void fma8(float* acc, const uint4& v, float p) {
    float2 f;
    f = up2(v.x); acc[0] += f.x * p; acc[1] += f.y * p;
    f = up2(v.y); acc[2] += f.x * p; acc[3] += f.y * p;
    f = up2(v.z); acc[4] += f.x * p; acc[5] += f.y * p;
    f = up2(v.w); acc[6] += f.x * p; acc[7] += f.y * p;
}
__device__ inline float dot4(const float4& a, const float4& b) {
    return a.x * b.x + a.y * b.y + a.z * b.z + a.w * b.w;
}

// ---------------- prep: zero deg + pack W (fp16 fragment-major) + pad al2/ar2 ----
// W element (k,m): cfrag c=m>>4, kstep s=k>>5, lane=((k>>3)&3)*16 + (m&15), j=k&7

__global__ __launch_bounds__(256) void prep(const float* __restrict__ W0,
                                            const float* __restrict__ W1,
                                            const float* __restrict__ W2,
                                            const float* __restrict__ al2,
                                            const float* __restrict__ ar2,
                                            __half* __restrict__ P0,
                                            __half* __restrict__ P1,
                                            __half* __restrict__ P2,
                                            float* __restrict__ al2p,
                                            float* __restrict__ ar2p,
                                            int* __restrict__ deg, int N) {
    int b = blockIdx.x;
    int gtid = b * 256 + threadIdx.x;
    for (int i = gtid; i < N; i += gridDim.x * 256) deg[i] = 0;

    if (b < 14) {
        const float* W;
        __half* P;
        int K, M, Msrc, lb = b;
        if (lb < 8) {
            W = W0; P = P0; K = 128; M = 128; Msrc = 128;
        } else if (lb < 12) {
            W = W1; P = P1; K = 128; M = 64; Msrc = 64; lb -= 8;
        } else {
            W = W2; P = P2; K = 64; M = 64; Msrc = 40; lb -= 12;
        }
        int t = lb * 256 + threadIdx.x;  // indexes (m, k8)
        int nk8 = K >> 3;
        if (t < M * nk8) {
            int m = t % M, k8 = t / M;
            int k = k8 * 8;
            int c = m >> 4, s = k >> 5, hi = (k >> 3) & 3, lane = hi * 16 + (m & 15);
            float v[8];
#pragma unroll
            for (int i = 0; i < 8; ++i)
                v[i] = (m < Msrc) ? W[(size_t)(k + i) * Msrc + m] : 0.f;
            uint4 o;
            o.x = pk2(v[0], v[1]);
            o.y = pk2(v[2], v[3]);
            o.z = pk2(v[4], v[5]);
            o.w = pk2(v[6], v[7]);
            *(uint4*)(P + (size_t)((c * (K >> 5) + s) * 64 + lane) * 8) = o;
        }
    } else if (b == 14) {
        int t = threadIdx.x;
        if (t < 64) {
            al2p[t] = (t < 40) ? al2[t] : 0.f;
            ar2p[t] = (t < 40) ? ar2[t] : 0.f;
        }
    }
}

// ---------------- CSR build (R2-proven: rank-based, atomic-free scatter) --------

__global__ __launch_bounds__(256) void degree_hist_rank(const int* __restrict__ dst,
                                                        int* __restrict__ deg,
                                                        int* __restrict__ rank, int E) {
    int e = blockIdx.x * blockDim.x + threadIdx.x;
    if (e >= E) return;
    int d = __builtin_nontemporal_load(&dst[e]);
    int r = atomicAdd(&deg[d], 1);
    __builtin_nontemporal_store(r, &rank[e]);
}

__global__ __launch_bounds__(256) void scan_block_sums(const int* __restrict__ in,
                                                       int* __restrict__ partial, int n) {
    int i = blockIdx.x * 256 + threadIdx.x;
    int v = (i < n) ? in[i] : 0;
#pragma unroll
    for (int off = 32; off; off >>= 1) v += __shfl_xor(v, off);
    __shared__ int wsum[4];
    if ((threadIdx.x & 63) == 0) wsum[threadIdx.x >> 6] = v;
    __syncthreads();
    if (threadIdx.x == 0) partial[blockIdx.x] = wsum[0] + wsum[1] + wsum[2] + wsum[3];
}

// merged offsets+final scan; each block reduces partial[0..bid) itself (nb<=256).
__global__ __launch_bounds__(256) void scan_final2(const int* __restrict__ in,
                                                   const int* __restrict__ partial,
                                                   int* __restrict__ out, int n) {
    __shared__ int buf[256];
    __shared__ int wsum[4];
    int t = threadIdx.x;
    int i = blockIdx.x * 256 + t;
    int v = (i < n) ? in[i] : 0;
    buf[t] = v;
    __syncthreads();
    for (int off = 1; off < 256; off <<= 1) {
        int x = (t >= off) ? buf[t - off] : 0;
        __syncthreads();
        buf[t] += x;
        __syncthreads();
    }
    int incl = buf[t];
    int pv = (t < blockIdx.x) ? partial[t] : 0;
#pragma unroll
    for (int off = 32; off; off >>= 1) pv += __shfl_xor(pv, off);
    if ((t & 63) == 0) wsum[t >> 6] = pv;
    __syncthreads();
    int pre = wsum[0] + wsum[1] + wsum[2] + wsum[3];
    if (i < n) out[i] = pre + incl - v;
    if (i == n - 1) out[n] = pre + incl;
}

__global__ __launch_bounds__(256) void scatter_rank(const int* __restrict__ src,
                                                    const int* __restrict__ dst,
                                                    const int* __restrict__ rank,
                                                    const int* __restrict__ row_start,
                                                    int* __restrict__ csr_src, int E) {
    int e = blockIdx.x * blockDim.x + threadIdx.x;
    if (e >= E) return;
    int d = __builtin_nontemporal_load(&dst[e]);
    int s = __builtin_nontemporal_load(&src[e]);
    int r = __builtin_nontemporal_load(&rank[e]);
    csr_src[row_start[d] + r] = s;
}

// ---------------- GEMM tile (device, per-wave 16 rows) ----------------
// B frags from packed global W (L1/L2 resident).
// A frag: row=lane&15, k=(lane>>4)*8+j.  D frag: col=lane&15, row=(lane>>4)*4+r.
// AMODE: 0 = global fp32, 2 = per-wave LDS fp16 (XOR-chunk swizzled)

template <int K, int M, int H, int AMODE, int LSTR>
__device__ __forceinline__ void gemm_tile(float* wt, const void* __restrict__ xin,
                                          const __half* aw,
                                          const __half* __restrict__ Wp,
                                          const float* __restrict__ al,
                                          const float* __restrict__ ar,
                                          __half* __restrict__ outh,
                                          float* __restrict__ el,
                                          float* __restrict__ er, int rowbase, int N) {
    constexpr int KS = K / 32;
    constexpr int CF = M / 16;
    constexpr int LDT = (M == 128) ? 133 : 69;  // padded fp32 transpose stride
    constexpr int NC8 = (M / 8) / 4;
    const int lane = threadIdx.x & 63;
    const int lhi = lane >> 4, llo = lane & 15;

    f4 acc[CF];
#pragma unroll
    for (int c = 0; c < CF; ++c) acc[c] = f4{0.f, 0.f, 0.f, 0.f};

    const int arow = rowbase + llo;
    const bool aval = arow < N;
#pragma unroll
    for (int s = 0; s < KS; ++s) {
        h8 a = {};
        if constexpr (AMODE == 2) {
            int c8 = s * 4 + lhi;
            a = *(const h8*)(aw + llo * LSTR + ((c8 ^ (llo & 7)) << 3));
        } else {
            if (aval) {
                const float4* xp = (const float4*)((const float*)xin + (size_t)arow * K +
                                                   s * 32 + lhi * 8);
                float4 x0 = xp[0];
                float4 x1 = xp[1];
                a[0] = (_Float16)x0.x; a[1] = (_Float16)x0.y;
                a[2] = (_Float16)x0.z; a[3] = (_Float16)x0.w;
                a[4] = (_Float16)x1.x; a[5] = (_Float16)x1.y;
                a[6] = (_Float16)x1.z; a[7] = (_Float16)x1.w;
            }
        }
#pragma unroll
        for (int c = 0; c < CF; ++c) {
            h8 b = *(const h8*)(Wp + (size_t)((c * KS + s) * 64 + lane) * 8);
            acc[c] = __builtin_amdgcn_mfma_f32_16x16x32_f16(a, b, acc[c], 0, 0, 0);
        }
    }
    asm volatile("" ::: "memory");  // A-reads from LDS complete before wt overwrite

    // scatter D frags into per-wave transpose tile (row = lhi*4+r, col = c*16+llo)
#pragma unroll
    for (int c = 0; c < CF; ++c) {
#pragma unroll
        for (int r = 0; r < 4; ++r)
            wt[(lhi * 4 + r) * LDT + c * 16 + llo] = acc[c][r];
    }
    asm volatile("" ::: "memory");
    // same-wave LDS RAW: DS pipe is in-order per wave

    // read back row-major: 4 lanes per row, interleaved 8-col chunks j8 = q + 4*i
    const int rrow = lane >> 2;
    const int q = lane & 3;
    const int grow = rowbase + rrow;
    float elp[H], erp[H];
#pragma unroll
    for (int h = 0; h < H; ++h) { elp[h] = 0.f; erp[h] = 0.f; }
    const float4* al4 = (const float4*)al;
    const float4* ar4 = (const float4*)ar;
#pragma unroll
    for (int i = 0; i < NC8; ++i) {
        int j8 = q + 4 * i;
        float4 v0 = *(float4*)&wt[rrow * LDT + 8 * j8];
        float4 v1 = *(float4*)&wt[rrow * LDT + 8 * j8 + 4];
        int h = (H == 2 && i >= NC8 / 2) ? 1 : 0;
        float4 a0 = al4[2 * j8], a1 = al4[2 * j8 + 1];
        float4 r0 = ar4[2 * j8], r1 = ar4[2 * j8 + 1];
        elp[h] += dot4(v0, a0) + dot4(v1, a1);
        erp[h] += dot4(v0, r0) + dot4(v1, r1);
        if (grow < N) {
            uint4 pkv;
            pkv.x = pk2(v0.x, v0.y);
            pkv.y = pk2(v0.z, v0.w);
            pkv.z = pk2(v1.x, v1.y);
            pkv.w = pk2(v1.z, v1.w);
            *(uint4*)(outh + (size_t)grow * M + 8 * j8) = pkv;
        }
    }
#pragma unroll
    for (int h = 0; h < H; ++h) {
#pragma unroll
        for (int off = 1; off < 4; off <<= 1) {
            elp[h] += __shfl_xor(elp[h], off);
            erp[h] += __shfl_xor(erp[h], off);
        }
    }
    if (q == 0 && grow < N) {
        if constexpr (H == 2) {
            *(float2*)&el[(size_t)grow * 2] = float2{elp[0], elp[1]};
            *(float2*)&er[(size_t)grow * 2] = float2{erp[0], erp[1]};
        } else {
            el[grow] = elp[0];
            er[grow] = erp[0];
        }
    }
}

// ---------------- aggregate core: one dst-pair per wave ----------------

template <int H, int D, int FSTRIDE, int T>
__device__ __forceinline__ void agg_one(const __half* __restrict__ feat,
                                        const float* __restrict__ el,
                                        const float* __restrict__ er,
                                        const int* __restrict__ row_start,
                                        const int* __restrict__ csr_src,
                                        const float* __restrict__ bias,
                                        int dstn, bool dval, int lane,
                                        float4& o0, float4& o1) {
    constexpr int NLp = FSTRIDE / 8;   // lanes per padded row (uint4 each)
    constexpr int GnH = 32 / NLp;      // edge groups per half-wave
    constexpr int BATCH = GnH * T;     // edges per gather round per half
    constexpr int WL = (H * D) / 8;    // writer lanes per dst
    static_assert(32 % NLp == 0 && BATCH <= 32, "layout");
    const int l32 = lane & 31;
    const int hb = lane & 32;
    const int g = l32 / NLp;
    const int ln = l32 % NLp;

    int beg = dval ? row_start[dstn] : 0;
    int end = dval ? row_start[dstn + 1] : 0;
    int cnt = end - beg;

    float er_d[H];
#pragma unroll
    for (int h = 0; h < H; ++h) er_d[h] = dval ? er[(size_t)dstn * H + h] : 0.f;

    float ssum[H];
    float acc8[8];
#pragma unroll
    for (int h = 0; h < H; ++h) ssum[h] = 0.f;
#pragma unroll
    for (int i = 0; i < 8; ++i) acc8[i] = 0.f;

    int trips = (cnt + 31) >> 5;
    {
        int to = __shfl_xor(trips, 32);
        trips = (to > trips) ? to : trips;
    }

    for (int it = 0; it < trips; ++it) {
        int base = beg + it * 32;
        int idx = base + l32;
        bool valid = idx < end;
        int s = csr_src[valid ? idx : beg];
        float p[H];
        if constexpr (H == 2) {
            float2 e2 = ((const float2*)el)[s];
            float e0 = e2.x + er_d[0];
            float e1 = e2.y + er_d[1];
            e0 = (e0 > 0.f) ? e0 : NEG_SLOPE * e0;
            e1 = (e1 > 0.f) ? e1 : NEG_SLOPE * e1;
            p[0] = valid ? __expf(e0) : 0.f;
            p[1] = valid ? __expf(e1) : 0.f;
            ssum[0] += p[0];
            ssum[1] += p[1];
        } else {
            float e = el[s] + er_d[0];
            e = (e > 0.f) ? e : NEG_SLOPE * e;
            p[0] = valid ? __expf(e) : 0.f;
            ssum[0] += p[0];
        }
        int cc = end - base;
        cc = (cc < 0) ? 0 : ((cc > 32) ? 32 : cc);
        int ccm = cc;
        {
            int o = __shfl_xor(ccm, 32);
            ccm = (o > ccm) ? o : ccm;
        }
        for (int j = 0; j < ccm; j += BATCH) {
            uint4 v[T];
#pragma unroll
            for (int t = 0; t < T; ++t) {
                if (j + GnH * t < cc) {
                    int sj = __shfl(s, hb + j + GnH * t + g);
                    v[t] = ((const uint4*)(feat + (size_t)sj * FSTRIDE))[ln];
                }
            }
#pragma unroll
            for (int t = 0; t < T; ++t) {
                if (j + GnH * t < cc) {
                    int slot = hb + j + GnH * t + g;
                    float pj = __shfl(p[0], slot);
                    if constexpr (H == 2) {
                        float pj1 = __shfl(p[1], slot);
                        pj = (ln >= 8) ? pj1 : pj;
                    }
                    fma8(acc8, v[t], pj);
                }
            }
        }
    }

#pragma unroll
    for (int h = 0; h < H; ++h)
#pragma unroll
        for (int off = 16; off; off >>= 1) ssum[h] += __shfl_xor(ssum[h], off);
#pragma unroll
    for (int i = 0; i < 8; ++i) {
#pragma unroll
        for (int off = NLp; off < 32; off <<= 1) acc8[i] += __shfl_xor(acc8[i], off);
    }
    o0 = float4{0.f, 0.f, 0.f, 0.f};
    o1 = float4{0.f, 0.f, 0.f, 0.f};
    constexpr int WLc = (H * D) / 8;
    if (l32 < WLc) {
        float sden;
        if constexpr (H == 2) sden = (l32 >= 8) ? ssum[1] : ssum[0];
        else sden = ssum[0];
        float inv = (dval && sden > 0.f) ? 1.f / sden : 0.f;
        float bsc = dval ? 1.f : 0.f;
        const float4* bp = (const float4*)bias;
        float4 bv0 = bp[2 * l32], bv1 = bp[2 * l32 + 1];
        o0.x = (acc8[0] * inv + bv0.x) * bsc; o0.y = (acc8[1] * inv + bv0.y) * bsc;
        o0.z = (acc8[2] * inv + bv0.z) * bsc; o0.w = (acc8[3] * inv + bv0.w) * bsc;
        o1.x = (acc8[4] * inv + bv1.x) * bsc; o1.y = (acc8[5] * inv + bv1.y) * bsc;
        o1.z = (acc8[6] * inv + bv1.z) * bsc; o1.w = (acc8[7] * inv + bv1.w) * bsc;
    }
}

// ---------------- standalone gemm layer 0 (4 waves/block, 64-row tile) ---------

__global__ __launch_bounds__(256) void gemm0_k(const float* __restrict__ in_feat,
                                               const __half* __restrict__ Wp0,
                                               const float* __restrict__ al0,
                                               const float* __restrict__ ar0,
                                               __half* __restrict__ feat0,
                                               float* __restrict__ el0,
                                               float* __restrict__ er0, int N) {
    constexpr int LDT = 133;
    __shared__ float tl[4 * 16 * LDT];
    const int wid = threadIdx.x >> 6;
    gemm_tile<128, 128, 2, 0, 0>(tl + wid * 16 * LDT, in_feat, nullptr, Wp0, al0, ar0,
                                 feat0, el0, er0, blockIdx.x * 64 + wid * 16, N);
}

// ---------------- fused: aggregate layer l -> (LDS) -> gemm layer l+1 ----------
// ONE WAVE per block, 16 dsts/rows per block, grid = ceil(N/16) = 3125.
// 4.4 KB LDS/block -> occupancy is VGPR-bound (~16 waves/CU), matching the
// standalone aggregate's latency hiding; kills the h round-trip + a boundary.

template <int HA, int DA, int FSA, int T, int KG, int LSTR>
__global__ __launch_bounds__(64) void agg_gemm(
    const __half* __restrict__ featA, const float* __restrict__ elA,
    const float* __restrict__ erA, const int* __restrict__ row_start,
    const int* __restrict__ csr_src, const float* __restrict__ biasA,
    const __half* __restrict__ Wp, const float* __restrict__ alG,
    const float* __restrict__ arG, __half* __restrict__ featO,
    float* __restrict__ elO, float* __restrict__ erO, int N) {
    constexpr int LDT = 69;
    constexpr int REGB = 16 * LDT * 4;  // 4416 B
    static_assert(16 * LSTR * 2 <= REGB, "h-tile must fit region");
    static_assert(HA * DA == KG, "agg out feeds gemm K");
    constexpr int WL = (HA * DA) / 8;
    __shared__ alignas(16) char smem[REGB];
    const int lane = threadIdx.x & 63;
    const int l32 = lane & 31;
    __half* lds_h = (__half*)smem;
    float* wt = (float*)smem;
    const int dbase = blockIdx.x * 16;

#pragma unroll 1
    for (int it = 0; it < 8; ++it) {
        int dl = it * 2 + (lane >> 5);   // local row 0..15
        int dstn = dbase + dl;
        bool dval = dstn < N;
        float4 o0, o1;
        agg_one<HA, DA, FSA, T>(featA, elA, erA, row_start, csr_src, biasA, dstn,
                                dval, lane, o0, o1);
        if (l32 < WL) {
            uint4 pkv;
            pkv.x = pk2(o0.x, o0.y);
            pkv.y = pk2(o0.z, o0.w);
            pkv.z = pk2(o1.x, o1.y);
            pkv.w = pk2(o1.z, o1.w);
            // XOR-chunk swizzle (chunk = 8 halfs) matches gemm A-read swizzle
            ((uint4*)(lds_h + dl * LSTR))[l32 ^ (dl & 7)] = pkv;
        }
    }
    asm volatile("" ::: "memory");

    gemm_tile<KG, 64, 1, 2, LSTR>(wt, nullptr, lds_h, Wp, alG, arG, featO, elO, erO,
                                  dbase, N);
}

// ---------------- standalone aggregate -> fp32 out (layer 2) ----------------

template <int H, int D, int FSTRIDE, int T>
__global__ __launch_bounds__(256) void gat_agg_out(const __half* __restrict__ feat,
                                                   const float* __restrict__ el,
                                                   const float* __restrict__ er,
                                                   const int* __restrict__ row_start,
                                                   const int* __restrict__ csr_src,
                                                   const float* __restrict__ bias,
                                                   float* __restrict__ out, int N) {
    int pair = (blockIdx.x * blockDim.x + threadIdx.x) >> 6;
    int lane = threadIdx.x & 63;
    if (pair * 2 >= N) return;
    int dstn = pair * 2 + (lane >> 5);
    bool dval = dstn < N;
    float4 o0, o1;
    agg_one<H, D, FSTRIDE, T>(feat, el, er, row_start, csr_src, bias, dstn, dval,
                              lane, o0, o1);
    constexpr int WL = (H * D) / 8;
    int l32 = lane & 31;
    if (l32 < WL && dval) {
        float4* op = (float4*)(out + (size_t)dstn * (H * D));
        op[2 * l32] = o0;
        op[2 * l32 + 1] = o1;
    }
}

// ---------------- launch ----------------

extern "C" void kernel_launch(void* const* d_in, const int* in_sizes, int n_in,
                              void* d_out, int out_size, void* d_ws, size_t ws_size,
                              hipStream_t stream) {
    const float* in_feat = (const float*)d_in[0];
    const int*   src     = (const int*)d_in[1];
    const int*   dst     = (const int*)d_in[2];
    const float* W0 = (const float*)d_in[3];
    const float* al0 = (const float*)d_in[4];
    const float* ar0 = (const float*)d_in[5];
    const float* b0 = (const float*)d_in[6];
    const float* W1 = (const float*)d_in[7];
    const float* al1 = (const float*)d_in[8];
    const float* ar1 = (const float*)d_in[9];
    const float* b1 = (const float*)d_in[10];
    const float* W2 = (const float*)d_in[11];
    const float* al2 = (const float*)d_in[12];
    const float* ar2 = (const float*)d_in[13];
    const float* b2 = (const float*)d_in[14];
    float* out = (float*)d_out;

    const int N = in_sizes[0] / 128;  // 50000
    const int E = in_sizes[1];        // 850000

    char* ws = (char*)d_ws;
    auto alloc = [&](size_t bytes) -> void* {
        void* p = (void*)ws;
        ws += (bytes + 255) & ~(size_t)255;
        return p;
    };
    int* deg       = (int*)alloc((size_t)N * 4);
    int* row_start = (int*)alloc((size_t)(N + 1) * 4);
    int* rank      = (int*)alloc((size_t)E * 4);
    int* csr_src   = (int*)alloc((size_t)E * 4);
    int* partial   = (int*)alloc(256 * 4);
    __half* feat0  = (__half*)alloc((size_t)N * 128 * 2);
    float* el0     = (float*)alloc((size_t)N * 2 * 4);
    float* er0     = (float*)alloc((size_t)N * 2 * 4);
    __half* feat1  = (__half*)alloc((size_t)N * 64 * 2);
    float* el1     = (float*)alloc((size_t)N * 4);
    float* er1     = (float*)alloc((size_t)N * 4);
    __half* feat2  = (__half*)alloc((size_t)N * 64 * 2);
    float* el2     = (float*)alloc((size_t)N * 4);
    float* er2     = (float*)alloc((size_t)N * 4);
    __half* Wp0    = (__half*)alloc((size_t)128 * 128 * 2);
    __half* Wp1    = (__half*)alloc((size_t)128 * 64 * 2);
    __half* Wp2    = (__half*)alloc((size_t)64 * 64 * 2);
    float* al2p    = (float*)alloc(64 * 4);
    float* ar2p    = (float*)alloc(64 * 4);

    int egrid = (E + 255) / 256;      // 3321
    int nb = (N + 255) / 256;         // 196
    int mgrid = (N + 63) / 64;        // 782  (gemm0 tiles)
    int atiles = (N + 15) / 16;       // 3125 (agg_gemm blocks, 1 wave each)
    int pgrid = (((N + 1) / 2) * 64 + 255) / 256;

    prep<<<256, 256, 0, stream>>>(W0, W1, W2, al2, ar2, Wp0, Wp1, Wp2, al2p, ar2p,
                                  deg, N);
    degree_hist_rank<<<egrid, 256, 0, stream>>>(dst, deg, rank, E);
    scan_block_sums<<<nb, 256, 0, stream>>>(deg, partial, N);
    scan_final2<<<nb, 256, 0, stream>>>(deg, partial, row_start, N);
    scatter_rank<<<egrid, 256, 0, stream>>>(src, dst, rank, row_start, csr_src, E);

    // layer 0 gemm: in=128 fp32, M=128, H=2
    gemm0_k<<<mgrid, 256, 0, stream>>>(in_feat, Wp0, al0, ar0, feat0, el0, er0, N);
    // agg L0 -> LDS -> gemm L1
    agg_gemm<2, 64, 128, 8, 128, 136><<<atiles, 64, 0, stream>>>(
        feat0, el0, er0, row_start, csr_src, b0, Wp1, al1, ar1, feat1, el1, er1, N);
    // agg L1 -> LDS -> gemm L2 (M=64 padded; cols 40-63 exact zeros)
    agg_gemm<1, 64, 64, 8, 64, 72><<<atiles, 64, 0, stream>>>(
        feat1, el1, er1, row_start, csr_src, b1, Wp2, al2p, ar2p, feat2, el2, er2, N);
    // agg L2 -> out
    gat_agg_out<1, 40, 64, 8><<<pgrid, 256, 0, stream>>>(feat2, el2, er2, row_start,
                                                         csr_src, b2, out, N);
}

// Round 6
// 263.874 us; speedup vs baseline: 1.4154x; 1.0901x over previous
//
#include <hip/hip_runtime.h>
#include <hip/hip_fp16.h>
#include <math.h>

#define NEG_SLOPE 0.2f

typedef _Float16 h8 __attribute__((ext_vector_type(8)));
typedef float f4 __attribute__((ext_vector_type(4)));

// ---------------- fp16 pack/unpack helpers ----------------

__device__ inline float2 up2(unsigned u) {
    __half2 h;
    __builtin_memcpy(&h, &u, 4);
    return __half22float2(h);
}
__device__ inline unsigned pk2(float a, float b) {
    __half2 h = __floats2half2_rn(a, b);
    unsigned u;
    __builtin_memcpy(&u, &h, 4);
    return u;
}
__device__ inline void fma8(float* acc, const uint4& v, float p) {
    float2 f;
    f = up2(v.x); acc[0] += f.x * p; acc[1] += f.y * p;
    f = up2(v.y); acc[2] += f.x * p; acc[3] += f.y * p;
    f = up2(v.z); acc[4] += f.x * p; acc[5] += f.y * p;
    f = up2(v.w); acc[6] += f.x * p; acc[7] += f.y * p;
}
__device__ inline float dot4(const float4& a, const float4& b) {
    return a.x * b.x + a.y * b.y + a.z * b.z + a.w * b.w;
}

// ---------------- prep: zero deg + pack W (fp16 fragment-major) + pad al2/ar2 ----
// W element (k,m): cfrag c=m>>4, kstep s=k>>5, lane=((k>>3)&3)*16 + (m&15), j=k&7

__global__ __launch_bounds__(256) void prep(const float* __restrict__ W0,
                                            const float* __restrict__ W1,
                                            const float* __restrict__ W2,
                                            const float* __restrict__ al2,
                                            const float* __restrict__ ar2,
                                            __half* __restrict__ P0,
                                            __half* __restrict__ P1,
                                            __half* __restrict__ P2,
                                            float* __restrict__ al2p,
                                            float* __restrict__ ar2p,
                                            int* __restrict__ deg, int N) {
    int b = blockIdx.x;
    int gtid = b * 256 + threadIdx.x;
    for (int i = gtid; i < N; i += gridDim.x * 256) deg[i] = 0;

    if (b < 14) {
        const float* W;
        __half* P;
        int K, M, Msrc, lb = b;
        if (lb < 8) {
            W = W0; P = P0; K = 128; M = 128; Msrc = 128;
        } else if (lb < 12) {
            W = W1; P = P1; K = 128; M = 64; Msrc = 64; lb -= 8;
        } else {
            W = W2; P = P2; K = 64; M = 64; Msrc = 40; lb -= 12;
        }
        int t = lb * 256 + threadIdx.x;  // indexes (m, k8)
        int nk8 = K >> 3;
        if (t < M * nk8) {
            int m = t % M, k8 = t / M;
            int k = k8 * 8;
            int c = m >> 4, s = k >> 5, hi = (k >> 3) & 3, lane = hi * 16 + (m & 15);
            float v[8];
#pragma unroll
            for (int i = 0; i < 8; ++i)
                v[i] = (m < Msrc) ? W[(size_t)(k + i) * Msrc + m] : 0.f;
            uint4 o;
            o.x = pk2(v[0], v[1]);
            o.y = pk2(v[2], v[3]);
            o.z = pk2(v[4], v[5]);
            o.w = pk2(v[6], v[7]);
            *(uint4*)(P + (size_t)((c * (K >> 5) + s) * 64 + lane) * 8) = o;
        }
    } else if (b == 14) {
        int t = threadIdx.x;
        if (t < 64) {
            al2p[t] = (t < 40) ? al2[t] : 0.f;
            ar2p[t] = (t < 40) ? ar2[t] : 0.f;
        }
    }
}

// ---------------- CSR build ----------------

__global__ __launch_bounds__(256) void degree_hist_rank(const int* __restrict__ dst,
                                                        int* __restrict__ deg,
                                                        int* __restrict__ rank, int E) {
    int e = blockIdx.x * blockDim.x + threadIdx.x;
    if (e >= E) return;
    int d = __builtin_nontemporal_load(&dst[e]);
    int r = atomicAdd(&deg[d], 1);
    __builtin_nontemporal_store(r, &rank[e]);
}

__global__ __launch_bounds__(256) void scan_block_sums(const int* __restrict__ in,
                                                       int* __restrict__ partial, int n) {
    int i = blockIdx.x * 256 + threadIdx.x;
    int v = (i < n) ? in[i] : 0;
#pragma unroll
    for (int off = 32; off; off >>= 1) v += __shfl_xor(v, off);
    __shared__ int wsum[4];
    if ((threadIdx.x & 63) == 0) wsum[threadIdx.x >> 6] = v;
    __syncthreads();
    if (threadIdx.x == 0) partial[blockIdx.x] = wsum[0] + wsum[1] + wsum[2] + wsum[3];
}

// merged offsets+final scan; each block reduces partial[0..bid) itself (nb<=256).
__global__ __launch_bounds__(256) void scan_final2(const int* __restrict__ in,
                                                   const int* __restrict__ partial,
                                                   int* __restrict__ out, int n) {
    __shared__ int buf[256];
    __shared__ int wsum[4];
    int t = threadIdx.x;
    int i = blockIdx.x * 256 + t;
    int v = (i < n) ? in[i] : 0;
    buf[t] = v;
    __syncthreads();
    for (int off = 1; off < 256; off <<= 1) {
        int x = (t >= off) ? buf[t - off] : 0;
        __syncthreads();
        buf[t] += x;
        __syncthreads();
    }
    int incl = buf[t];
    int pv = (t < blockIdx.x) ? partial[t] : 0;
#pragma unroll
    for (int off = 32; off; off >>= 1) pv += __shfl_xor(pv, off);
    if ((t & 63) == 0) wsum[t >> 6] = pv;
    __syncthreads();
    int pre = wsum[0] + wsum[1] + wsum[2] + wsum[3];
    if (i < n) out[i] = pre + incl - v;
    if (i == n - 1) out[n] = pre + incl;
}

__global__ __launch_bounds__(256) void scatter_rank(const int* __restrict__ src,
                                                    const int* __restrict__ dst,
                                                    const int* __restrict__ rank,
                                                    const int* __restrict__ row_start,
                                                    int* __restrict__ csr_src, int E) {
    int e = blockIdx.x * blockDim.x + threadIdx.x;
    if (e >= E) return;
    int d = __builtin_nontemporal_load(&dst[e]);
    int s = __builtin_nontemporal_load(&src[e]);
    int r = __builtin_nontemporal_load(&rank[e]);
    csr_src[row_start[d] + r] = s;
}

// ---------------- MFMA GEMM + fused attn-score epilogue ----------------
// 4 waves/block, 16 rows/wave, 64 rows/block. B fragments read straight from
// packed global W (L1/L2 resident); no inter-wave LDS sharing -> no barriers.
// A frag: row=lane&15, k=(lane>>4)*8+j.  D frag: col=lane&15, row=(lane>>4)*4+r.

template <int K, int M, int H, bool A16>
__global__ __launch_bounds__(256) void gemm_mfma(const void* __restrict__ xin,
                                                 const __half* __restrict__ Wp,
                                                 const float* __restrict__ al,
                                                 const float* __restrict__ ar,
                                                 __half* __restrict__ outh,
                                                 float* __restrict__ el,
                                                 float* __restrict__ er, int N) {
    constexpr int KS = K / 32;   // k-steps
    constexpr int CF = M / 16;   // column fragments
    constexpr int LDT = 133;     // padded fp32 LDS row stride
    constexpr int CH8 = M / 8;   // 8-col chunks per row
    constexpr int NC8 = CH8 / 4; // chunks per lane in read-back (4 lanes/row)
    __shared__ float tl[4 * 16 * LDT];
    const int tid = threadIdx.x;
    const int wid = tid >> 6, lane = tid & 63;
    const int lhi = lane >> 4, llo = lane & 15;
    const int rowbase = blockIdx.x * 64 + wid * 16;
    float* wt = tl + wid * 16 * LDT;

    f4 acc[CF];
#pragma unroll
    for (int c = 0; c < CF; ++c) acc[c] = f4{0.f, 0.f, 0.f, 0.f};

    const int arow = rowbase + llo;
    const bool aval = arow < N;
#pragma unroll
    for (int s = 0; s < KS; ++s) {
        h8 a = {};
        if (aval) {
            if constexpr (A16) {
                const __half* xp = (const __half*)xin + (size_t)arow * K + s * 32 + lhi * 8;
                a = *(const h8*)xp;
            } else {
                const float4* xp = (const float4*)((const float*)xin + (size_t)arow * K +
                                                   s * 32 + lhi * 8);
                float4 x0 = xp[0];
                float4 x1 = xp[1];
                a[0] = (_Float16)x0.x; a[1] = (_Float16)x0.y;
                a[2] = (_Float16)x0.z; a[3] = (_Float16)x0.w;
                a[4] = (_Float16)x1.x; a[5] = (_Float16)x1.y;
                a[6] = (_Float16)x1.z; a[7] = (_Float16)x1.w;
            }
        }
#pragma unroll
        for (int c = 0; c < CF; ++c) {
            h8 b = *(const h8*)(Wp + (size_t)((c * KS + s) * 64 + lane) * 8);
            acc[c] = __builtin_amdgcn_mfma_f32_16x16x32_f16(a, b, acc[c], 0, 0, 0);
        }
    }

    // scatter D frags into the per-wave LDS tile (row = lhi*4+r, col = c*16+llo)
#pragma unroll
    for (int c = 0; c < CF; ++c) {
#pragma unroll
        for (int r = 0; r < 4; ++r)
            wt[(lhi * 4 + r) * LDT + c * 16 + llo] = acc[c][r];
    }

    // read back row-major: 4 lanes per row, interleaved 8-col chunks j8 = q + 4*i
    const int rrow = lane >> 2;
    const int q = lane & 3;
    const int grow = rowbase + rrow;
    float elp[H], erp[H];
#pragma unroll
    for (int h = 0; h < H; ++h) { elp[h] = 0.f; erp[h] = 0.f; }
    const float4* al4 = (const float4*)al;
    const float4* ar4 = (const float4*)ar;
#pragma unroll
    for (int i = 0; i < NC8; ++i) {
        int j8 = q + 4 * i;
        float4 v0 = *(float4*)&wt[rrow * LDT + 8 * j8];
        float4 v1 = *(float4*)&wt[rrow * LDT + 8 * j8 + 4];
        int h = (H == 2 && i >= NC8 / 2) ? 1 : 0;
        float4 a0 = al4[2 * j8], a1 = al4[2 * j8 + 1];
        float4 r0 = ar4[2 * j8], r1 = ar4[2 * j8 + 1];
        elp[h] += dot4(v0, a0) + dot4(v1, a1);
        erp[h] += dot4(v0, r0) + dot4(v1, r1);
        if (grow < N) {
            uint4 pkv;
            pkv.x = pk2(v0.x, v0.y);
            pkv.y = pk2(v0.z, v0.w);
            pkv.z = pk2(v1.x, v1.y);
            pkv.w = pk2(v1.z, v1.w);
            *(uint4*)(outh + (size_t)grow * M + 8 * j8) = pkv;
        }
    }
#pragma unroll
    for (int h = 0; h < H; ++h) {
#pragma unroll
        for (int off = 1; off < 4; off <<= 1) {
            elp[h] += __shfl_xor(elp[h], off);
            erp[h] += __shfl_xor(erp[h], off);
        }
    }
    if (q == 0 && grow < N) {
        if constexpr (H == 2) {
            *(float2*)&el[(size_t)grow * 2] = float2{elp[0], elp[1]};
            *(float2*)&er[(size_t)grow * 2] = float2{erp[0], erp[1]};
        } else {
            el[grow] = elp[0];
            er[grow] = erp[0];
        }
    }
}

// ---------------- per-dst softmax + aggregation (HALF-wave per dst) ----------------
// Latency-overlap order per 32-edge trip:
//   (1) issue el[s] load (oldest outstanding vmem)
//   (2) issue ALL feature-row gathers for the trip (BATCH == 32)
//   (3) compute p  -> waits only el (vmcnt(T)), gathers still in flight
//   (4) fma        -> waits gathers (vmcnt(0))
// One memory-latency exposure per trip instead of two/three.

template <int H, int D, int FSTRIDE, int T, bool OUT16>
__global__ __launch_bounds__(256) void gat_aggregate3(const __half* __restrict__ feat,
                                                      const float* __restrict__ el,
                                                      const float* __restrict__ er,
                                                      const int* __restrict__ row_start,
                                                      const int* __restrict__ csr_src,
                                                      const float* __restrict__ bias,
                                                      void* __restrict__ out, int N) {
    constexpr int NLp = FSTRIDE / 8;   // lanes per padded row (uint4 each)
    constexpr int GnH = 32 / NLp;      // edge groups per half-wave
    constexpr int BATCH = GnH * T;     // edges per gather round per half
    constexpr int WL = (H * D) / 8;    // writer lanes per dst
    static_assert(32 % NLp == 0 && BATCH == 32, "whole trip in one round");
    int pair = (blockIdx.x * blockDim.x + threadIdx.x) >> 6;
    int lane = threadIdx.x & 63;
    if (pair * 2 >= N) return;
    const int l32 = lane & 31;
    const int hb = lane & 32;
    const int dstn = pair * 2 + (lane >> 5);
    const bool dval = dstn < N;
    int beg = dval ? row_start[dstn] : 0;
    int end = dval ? row_start[dstn + 1] : 0;
    int cnt = end - beg;

    float er_d[H];
#pragma unroll
    for (int h = 0; h < H; ++h) er_d[h] = dval ? er[(size_t)dstn * H + h] : 0.f;

    float ssum[H];
    float acc8[8];
#pragma unroll
    for (int h = 0; h < H; ++h) ssum[h] = 0.f;
#pragma unroll
    for (int i = 0; i < 8; ++i) acc8[i] = 0.f;

    const int g = l32 / NLp;
    const int ln = l32 % NLp;
    const uint4* fp = (const uint4*)feat;

    int trips = (cnt + 31) >> 5;
    {
        int to = __shfl_xor(trips, 32);
        trips = (to > trips) ? to : trips;
    }

    for (int it = 0; it < trips; ++it) {
        int base = beg + it * 32;
        int idx = base + l32;
        bool valid = idx < end;
        int s = csr_src[valid ? idx : beg];
        int cc = end - base;
        cc = (cc < 0) ? 0 : ((cc > 32) ? 32 : cc);

        // (1) score-input load first: oldest outstanding vmem op
        float ev0 = 0.f, ev1 = 0.f;
        if constexpr (H == 2) {
            float2 e2 = ((const float2*)el)[s];
            ev0 = e2.x;
            ev1 = e2.y;
        } else {
            ev0 = el[s];
        }

        // (2) issue the whole trip's feature-row gathers (depend only on s)
        uint4 v[T];
#pragma unroll
        for (int t = 0; t < T; ++t) {
            if (GnH * t < cc) {
                int sj = __shfl(s, hb + GnH * t + g);
                v[t] = fp[(size_t)sj * NLp + ln];
            }
        }

        // (3) scores: waits only on el (gathers remain in flight)
        float p[H];
        if constexpr (H == 2) {
            float e0 = ev0 + er_d[0];
            float e1 = ev1 + er_d[1];
            e0 = (e0 > 0.f) ? e0 : NEG_SLOPE * e0;
            e1 = (e1 > 0.f) ? e1 : NEG_SLOPE * e1;
            p[0] = valid ? __expf(e0) : 0.f;
            p[1] = valid ? __expf(e1) : 0.f;
            ssum[0] += p[0];
            ssum[1] += p[1];
        } else {
            float e = ev0 + er_d[0];
            e = (e > 0.f) ? e : NEG_SLOPE * e;
            p[0] = valid ? __expf(e) : 0.f;
            ssum[0] += p[0];
        }

        // (4) weighted accumulate
#pragma unroll
        for (int t = 0; t < T; ++t) {
            if (GnH * t < cc) {
                int slot = hb + GnH * t + g;
                float pj = __shfl(p[0], slot);
                if constexpr (H == 2) {
                    float pj1 = __shfl(p[1], slot);
                    pj = (ln >= 8) ? pj1 : pj;
                }
                fma8(acc8, v[t], pj);
            }
        }
    }

#pragma unroll
    for (int h = 0; h < H; ++h)
#pragma unroll
        for (int off = 16; off; off >>= 1) ssum[h] += __shfl_xor(ssum[h], off);
#pragma unroll
    for (int i = 0; i < 8; ++i) {
#pragma unroll
        for (int off = NLp; off < 32; off <<= 1) acc8[i] += __shfl_xor(acc8[i], off);
    }
    if (l32 < WL && dval) {
        float inv;
        if constexpr (H == 2) inv = 1.f / ((l32 >= 8) ? ssum[1] : ssum[0]);
        else inv = 1.f / ssum[0];
        const float4* bp = (const float4*)bias;
        float4 bv0 = bp[2 * l32], bv1 = bp[2 * l32 + 1];
        float4 o0, o1;
        o0.x = acc8[0] * inv + bv0.x; o0.y = acc8[1] * inv + bv0.y;
        o0.z = acc8[2] * inv + bv0.z; o0.w = acc8[3] * inv + bv0.w;
        o1.x = acc8[4] * inv + bv1.x; o1.y = acc8[5] * inv + bv1.y;
        o1.z = acc8[6] * inv + bv1.z; o1.w = acc8[7] * inv + bv1.w;
        if constexpr (OUT16) {
            __half* op = (__half*)out + (size_t)dstn * (H * D);
            uint4 pkv;
            pkv.x = pk2(o0.x, o0.y);
            pkv.y = pk2(o0.z, o0.w);
            pkv.z = pk2(o1.x, o1.y);
            pkv.w = pk2(o1.z, o1.w);
            ((uint4*)op)[l32] = pkv;
        } else {
            float4* op = (float4*)((float*)out + (size_t)dstn * (H * D));
            op[2 * l32] = o0;
            op[2 * l32 + 1] = o1;
        }
    }
}

// ---------------- launch ----------------

extern "C" void kernel_launch(void* const* d_in, const int* in_sizes, int n_in,
                              void* d_out, int out_size, void* d_ws, size_t ws_size,
                              hipStream_t stream) {
    const float* in_feat = (const float*)d_in[0];
    const int*   src     = (const int*)d_in[1];
    const int*   dst     = (const int*)d_in[2];
    const float* W0 = (const float*)d_in[3];
    const float* al0 = (const float*)d_in[4];
    const float* ar0 = (const float*)d_in[5];
    const float* b0 = (const float*)d_in[6];
    const float* W1 = (const float*)d_in[7];
    const float* al1 = (const float*)d_in[8];
    const float* ar1 = (const float*)d_in[9];
    const float* b1 = (const float*)d_in[10];
    const float* W2 = (const float*)d_in[11];
    const float* al2 = (const float*)d_in[12];
    const float* ar2 = (const float*)d_in[13];
    const float* b2 = (const float*)d_in[14];
    float* out = (float*)d_out;

    const int N = in_sizes[0] / 128;  // 50000
    const int E = in_sizes[1];        // 850000

    char* ws = (char*)d_ws;
    auto alloc = [&](size_t bytes) -> void* {
        void* p = (void*)ws;
        ws += (bytes + 255) & ~(size_t)255;
        return p;
    };
    int* deg       = (int*)alloc((size_t)N * 4);
    int* row_start = (int*)alloc((size_t)(N + 1) * 4);
    int* csr_src   = (int*)alloc((size_t)E * 4);
    int* rank      = (int*)alloc((size_t)E * 4);
    int* partial   = (int*)alloc(256 * 4);
    __half* feat   = (__half*)alloc((size_t)N * 128 * 2);
    float* el      = (float*)alloc((size_t)N * 2 * 4);
    float* er      = (float*)alloc((size_t)N * 2 * 4);
    __half* h0h    = (__half*)alloc((size_t)N * 128 * 2);
    __half* h1h    = (__half*)alloc((size_t)N * 64 * 2);
    __half* Wp0    = (__half*)alloc((size_t)128 * 128 * 2);
    __half* Wp1    = (__half*)alloc((size_t)128 * 64 * 2);
    __half* Wp2    = (__half*)alloc((size_t)64 * 64 * 2);
    float* al2p    = (float*)alloc(64 * 4);
    float* ar2p    = (float*)alloc(64 * 4);

    int egrid = (E + 255) / 256;
    int nb = (N + 255) / 256;

    prep<<<256, 256, 0, stream>>>(W0, W1, W2, al2, ar2, Wp0, Wp1, Wp2, al2p, ar2p, deg, N);
    degree_hist_rank<<<egrid, 256, 0, stream>>>(dst, deg, rank, E);
    scan_block_sums<<<nb, 256, 0, stream>>>(deg, partial, N);
    scan_final2<<<nb, 256, 0, stream>>>(deg, partial, row_start, N);
    scatter_rank<<<egrid, 256, 0, stream>>>(src, dst, rank, row_start, csr_src, E);

    int npairs = (N + 1) / 2;
    int pgrid = (npairs * 64 + 255) / 256;  // one wave per dst-pair
    int mgrid = (N + 63) / 64;              // 64 rows per MFMA gemm block

    // layer 0: in=128(fp32), M=128, H=2  | agg: FSTRIDE=128 -> T=16 (BATCH=32)
    gemm_mfma<128, 128, 2, false><<<mgrid, 256, 0, stream>>>(in_feat, Wp0, al0, ar0, feat, el, er, N);
    gat_aggregate3<2, 64, 128, 16, true><<<pgrid, 256, 0, stream>>>(feat, el, er, row_start, csr_src, b0, h0h, N);

    // layer 1: in=128(fp16), M=64, H=1   | agg: FSTRIDE=64 -> T=8 (BATCH=32)
    gemm_mfma<128, 64, 1, true><<<mgrid, 256, 0, stream>>>(h0h, Wp1, al1, ar1, feat, el, er, N);
    gat_aggregate3<1, 64, 64, 8, true><<<pgrid, 256, 0, stream>>>(feat, el, er, row_start, csr_src, b1, h1h, N);

    // layer 2: in=64(fp16), M=64 (cols 40-63 exact zeros), H=1
    gemm_mfma<64, 64, 1, true><<<mgrid, 256, 0, stream>>>(h1h, Wp2, al2p, ar2p, feat, el, er, N);
    gat_aggregate3<1, 40, 64, 8, false><<<pgrid, 256, 0, stream>>>(feat, el, er, row_start, csr_src, b2, out, N);
}